// Round 4
// baseline (408.715 us; speedup 1.0000x reference)
//
#include <hip/hip_runtime.h>
#include <hip/hip_bf16.h>

#define T_TRIP 500000
#define NP     100000
#define NTILES 7813    // ceil(T_TRIP/64)
#define NPAD   500032  // NTILES*64

typedef float f32x4 __attribute__((ext_vector_type(4)));
typedef __bf16 bf16x8 __attribute__((ext_vector_type(8)));
typedef unsigned short u16;
typedef unsigned short u16x8 __attribute__((ext_vector_type(8)));
typedef unsigned int u32;

__device__ __forceinline__ u16 f2bf(float f) {
  union { float f; unsigned u; } v; v.f = f;
  unsigned r = v.u + 0x7fffu + ((v.u >> 16) & 1u);
  return (u16)(r >> 16);
}

__device__ __forceinline__ ushort4 cvt4(float4 v) {
  ushort4 o; o.x = f2bf(v.x); o.y = f2bf(v.y); o.z = f2bf(v.z); o.w = f2bf(v.w);
  return o;
}

__device__ __forceinline__ u16 cvt1_pk(float v) {
  unsigned r;
  asm("v_cvt_pk_bf16_f32 %0, %1, %1" : "=v"(r) : "v"(v));
  return (u16)r;
}

__device__ __forceinline__ float bflo(u32 d) {
  union { u32 u; float f; } v; v.u = d << 16; return v.f;
}
__device__ __forceinline__ float bfhi(u32 d) {
  union { u32 u; float f; } v; v.u = d & 0xffff0000u; return v.f;
}

#define MFMA16(a, b, c) __builtin_amdgcn_mfma_f32_16x16x32_bf16((a), (b), (c), 0, 0, 0)

#define WAITVM(N) asm volatile("s_waitcnt vmcnt(" #N ")" ::: "memory")
#define LGKM0()   asm volatile("s_waitcnt lgkmcnt(0)" ::: "memory")

__device__ __forceinline__ void barrier_raw() {
  asm volatile("" ::: "memory");
  __builtin_amdgcn_s_barrier();
  asm volatile("" ::: "memory");
  __builtin_amdgcn_sched_barrier(0);
}

__device__ __forceinline__ void gload_lds16(const u16* g, u16* l) {
  __builtin_amdgcn_global_load_lds((const __attribute__((address_space(1))) void*)g,
                                   (__attribute__((address_space(3))) void*)l, 16, 0, 0);
}
__device__ __forceinline__ void gload_lds4(const int* g, int* l) {
  __builtin_amdgcn_global_load_lds((const __attribute__((address_space(1))) void*)g,
                                   (__attribute__((address_space(3))) void*)l, 4, 0, 0);
}

// =================== ws layout ===================
// u16-element offsets (weights + H region), as in R2:
#define FP_W1A   0u
#define FP_W1B   16384u
#define FP_W1C   32768u
#define FP_W2    49152u
#define FP_PW1   65536u
#define FP_PW2   98304u
#define FP_W1D   114688u
#define FP_H     131072u     // h_pair bf16 [NP][128]
#define FP_AGG   12931072u   // (mid path only) agg bf16 [NP][128]
#define WS_NEED_BYTES 51462144ull

// sorted-path byte offsets (M replaces/extends the AGG region):
#define FP_M_BYTE 25862144ull              // u32 m[NPAD][64]  (bf16-pair packed rows)
#define SB_CNT    153870336ull
#define SB_START  154270464ull             // int start[NP+1] (also scan temp)
#define SB_CURSOR 154670592ull
#define SB_BSUM   155070720ull
#define SB_IVU    155071232ull             // int [NPAD]
#define SB_IUW    157071360ull
#define SB_IVW    159071488ull
#define SB_GEOM   161071616ull             // float4 [NPAD]
#define WS_SORT_BYTES 169072128ull

#define HSTR  136
#define GSTR  520
#define X2STR 264

// ---------------- prep: weights -> bf16 transposed + geom weights f32 ----------------
__global__ void k_prep_fast(const float* __restrict__ psi_w1, const float* __restrict__ psi_w2,
                            const float* __restrict__ phi_w1, const float* __restrict__ phi_w2,
                            u16* __restrict__ ws) {
  int i = blockIdx.x * 256 + threadIdx.x;
  if (i < 49152) {
    int s = i / 16384, r = i % 16384;
    int n = r / 128, k = r % 128;
    ws[FP_W1A + i] = f2bf(psi_w1[(s * 128 + k) * 128 + n]);
    return;
  }
  i -= 49152;
  if (i < 16384) {
    int n = i / 128, k = i % 128;
    ws[FP_W2 + i] = f2bf(psi_w2[k * 128 + n]);
    return;
  }
  i -= 16384;
  if (i < 32768) {
    int n = i / 256, k = i % 256;
    ws[FP_PW1 + i] = f2bf(phi_w1[k * 128 + n]);
    return;
  }
  i -= 32768;
  if (i < 16384) {
    int n = i / 128, k = i % 128;
    ws[FP_PW2 + i] = f2bf(phi_w2[k * 128 + n]);
    return;
  }
  i -= 16384;
  if (i < 512) {
    int k = i / 128, n = i % 128;
    reinterpret_cast<float*>(ws + FP_W1D)[i] = psi_w1[(384 + k) * 128 + n];
  }
}

// ---------------- h_pair -> bf16 (+zero agg for mid path) ----------------
__global__ void k_hconv(const float* __restrict__ h, u16* __restrict__ H, u16* __restrict__ AGG) {
  const size_t i = (size_t)(blockIdx.x * 256 + threadIdx.x) * 8;
  float4 v0 = *reinterpret_cast<const float4*>(h + i);
  float4 v1 = *reinterpret_cast<const float4*>(h + i + 4);
  *reinterpret_cast<ushort4*>(H + i)     = cvt4(v0);
  *reinterpret_cast<ushort4*>(H + i + 4) = cvt4(v1);
  ushort4 z = {0, 0, 0, 0};
  *reinterpret_cast<ushort4*>(AGG + i)     = z;
  *reinterpret_cast<ushort4*>(AGG + i + 4) = z;
}

__global__ void k_hconv2(const float* __restrict__ h, u16* __restrict__ H) {
  const size_t i = (size_t)(blockIdx.x * 256 + threadIdx.x) * 8;
  float4 v0 = *reinterpret_cast<const float4*>(h + i);
  float4 v1 = *reinterpret_cast<const float4*>(h + i + 4);
  *reinterpret_cast<ushort4*>(H + i)     = cvt4(v0);
  *reinterpret_cast<ushort4*>(H + i + 4) = cvt4(v1);
}

// ================= sort: histogram + scan + permute =================
__global__ void k_hist(const int* __restrict__ ivw, int* __restrict__ cnt) {
  int i = blockIdx.x * 256 + threadIdx.x;
  if (i < T_TRIP) atomicAdd(&cnt[ivw[i]], 1);
}

__global__ __launch_bounds__(1024) void k_scan1(const int* __restrict__ cnt,
                                                int* __restrict__ tmp, int* __restrict__ bsum) {
  __shared__ int wsum[16];
  const int idx = blockIdx.x * 1024 + threadIdx.x;
  const int lane = threadIdx.x & 63, wid = threadIdx.x >> 6;
  int v = (idx < NP) ? cnt[idx] : 0;
  int x = v;
#pragma unroll
  for (int off = 1; off < 64; off <<= 1) {
    int n = __shfl_up(x, off);
    if (lane >= off) x += n;
  }
  if (lane == 63) wsum[wid] = x;
  __syncthreads();
  if (threadIdx.x < 16) {
    int s = wsum[threadIdx.x];
#pragma unroll
    for (int off = 1; off < 16; off <<= 1) {
      int n = __shfl_up(s, off);
      if (threadIdx.x >= off) s += n;
    }
    wsum[threadIdx.x] = s;
  }
  __syncthreads();
  const int base = wid ? wsum[wid - 1] : 0;
  if (idx < NP) tmp[idx] = base + x - v;           // exclusive within block
  if (threadIdx.x == 1023) bsum[blockIdx.x] = base + x;
}

__global__ void k_scan2(int* __restrict__ bsum) {   // 1 block, 128 thr, scans 98 totals
  __shared__ int s[128];
  const int t = threadIdx.x;
  int v = (t < 98) ? bsum[t] : 0;
  s[t] = v; __syncthreads();
#pragma unroll
  for (int off = 1; off < 128; off <<= 1) {
    int a = (t >= off) ? s[t - off] : 0;
    __syncthreads();
    s[t] += a;
    __syncthreads();
  }
  if (t < 98) bsum[t] = s[t] - v;                   // exclusive
}

__global__ void k_scan3(const int* __restrict__ bsum, int* __restrict__ start,
                        int* __restrict__ cursor) {
  int idx = blockIdx.x * 256 + threadIdx.x;
  if (idx < NP) {
    int f = start[idx] + bsum[idx >> 10];
    start[idx] = f;
    cursor[idx] = f;
  }
  if (idx == 0) start[NP] = T_TRIP;
}

__global__ void k_perm(const int* __restrict__ ivu, const int* __restrict__ iuw,
                       const int* __restrict__ ivw, const float* __restrict__ geom,
                       int* __restrict__ cursor,
                       int* __restrict__ ivu_s, int* __restrict__ iuw_s,
                       int* __restrict__ ivw_s, float4* __restrict__ geom_s) {
  int i = blockIdx.x * 256 + threadIdx.x;
  if (i < T_TRIP) {
    int v = ivw[i];
    int pos = atomicAdd(&cursor[v], 1);
    ivu_s[pos] = ivu[i];
    iuw_s[pos] = iuw[i];
    ivw_s[pos] = v;
    geom_s[pos] = reinterpret_cast<const float4*>(geom)[i];
  } else if (i < NPAD) {
    ivu_s[i] = 0; iuw_s[i] = 0; ivw_s[i] = 0;
    geom_s[i] = make_float4(0.f, 0.f, 0.f, 0.f);
  }
}

// ================= sorted triplet kernel: gather + MLP + streaming m stores =================
__global__ __launch_bounds__(256, 3) void k_triplet_sorted(
    const u16* __restrict__ H,
    const int* __restrict__ ivu_s, const int* __restrict__ iuw_s, const int* __restrict__ ivw_s,
    const float* __restrict__ geom_s,
    const u16* __restrict__ W1A, const u16* __restrict__ W1B, const u16* __restrict__ W1C,
    const float* __restrict__ w1dF, const u16* __restrict__ W2T,
    const float* __restrict__ b1, const float* __restrict__ b2,
    u32* __restrict__ M32) {
  __shared__ __align__(16) u16 XB[2][16 * GSTR];     // 33280 B
  __shared__ __align__(16) u16 hl[64 * HSTR];        // 17408 B
  __shared__ __align__(16) float geomF[64][4];       //  1024 B
  __shared__ __align__(16) int aIvu[2][64];          //   512 B
  __shared__ __align__(16) int aIuw[64];             //   256 B
  __shared__ __align__(16) int aIvw[64];             //   256 B

  const int tid = threadIdx.x;
  const int w = tid >> 6, l = tid & 63;
  const int lr = l & 15;
  const int lk = (l >> 4) << 3;
  const int n0 = w * 32 + lr;
  const int rowh = (l >> 4) << 2;
  const int srow = l >> 4;
  const int schunk = (l & 15) ^ ((l >> 4) << 1);

  // hoisted constants; W2 frags in regs -> GEMM2 has no vmem
  bf16x8 w2f[4][2];
#pragma unroll
  for (int ks = 0; ks < 4; ++ks)
#pragma unroll
    for (int ct = 0; ct < 2; ++ct)
      w2f[ks][ct] = *reinterpret_cast<const bf16x8*>(&W2T[(size_t)(n0 + ct * 16) * 128 + ks * 32 + lk]);
  const float b1v[2] = {b1[n0], b1[n0 + 16]};
  const float b2v[2] = {b2[n0], b2[n0 + 16]};
  float w1dv[4][2];
#pragma unroll
  for (int k = 0; k < 4; ++k) {
    w1dv[k][0] = w1dF[k * 128 + n0];
    w1dv[k][1] = w1dF[k * 128 + n0 + 16];
  }

  auto stage_src_lds = [&](const int* idxL, int buf) {
#pragma unroll
    for (int q = 0; q < 4; ++q) {
      const int g = w * 4 + q;
      const int idx = idxL[g * 4 + srow];
      gload_lds16(H + (size_t)idx * 128 + schunk * 8, &XB[buf][g * GSTR]);
    }
  };

  // exactly ONE vm op per wave: w0: ivu(tB)->aIvu[buf]; w1: iuw(tA); w2: ivw(tA); w3: geom(tA)
  auto stage_aux = [&](int tA, int tB, int buf) {
    if (w == 0) {
      gload_lds4(ivu_s + tB * 64 + l, &aIvu[buf][0]);
    } else if (w == 1) {
      gload_lds4(iuw_s + tA * 64 + l, &aIuw[0]);
    } else if (w == 2) {
      gload_lds4(ivw_s + tA * 64 + l, &aIvw[0]);
    } else {
      gload_lds16(reinterpret_cast<const u16*>(geom_s + (size_t)(tA * 64 + l) * 4),
                  reinterpret_cast<u16*>(&geomF[0][0]));
    }
  };

  auto gemm_src = [&](const u16* WT, int buf, f32x4 (&acc)[4][2]) {
#pragma unroll
    for (int ks = 0; ks < 4; ++ks) {
      bf16x8 a[4], b[2];
#pragma unroll
      for (int rt = 0; rt < 4; ++rt) {
        const int r = rt * 16 + lr;
        const int g = r >> 2, s = r & 3;
        const int j = ks * 4 + (l >> 4);
        a[rt] = *reinterpret_cast<const bf16x8*>(&XB[buf][g * GSTR + s * 128 + ((j ^ (s << 1)) << 3)]);
      }
#pragma unroll
      for (int ct = 0; ct < 2; ++ct)
        b[ct] = *reinterpret_cast<const bf16x8*>(&WT[(size_t)(n0 + ct * 16) * 128 + ks * 32 + lk]);
#pragma unroll
      for (int rt = 0; rt < 4; ++rt)
#pragma unroll
        for (int ct = 0; ct < 2; ++ct)
          acc[rt][ct] = MFMA16(a[rt], b[ct], acc[rt][ct]);
    }
  };

  int pb = 0, tb = 0;
  int tt = blockIdx.x;
  const int G = gridDim.x;

  // ---- prologue ----
  {
    int tB = (tt + G < NTILES) ? tt + G : NTILES - 1;
    stage_aux(tt, tB, 0);
#pragma unroll
    for (int q = 0; q < 4; ++q) {
      const int g = w * 4 + q;
      const int t = tt * 64 + g * 4 + srow;     // < NPAD, arrays padded
      const int idx = ivu_s[t];
      gload_lds16(H + (size_t)idx * 128 + schunk * 8, &XB[0][g * GSTR]);
    }
    WAITVM(0);
    barrier_raw();
  }

  for (; tt < NTILES; tt += G) {
    const int t0 = tt * 64;

    stage_src_lds(aIuw, pb ^ 1);             // A: s1(t)
    f32x4 acc[4][2] = {};
    gemm_src(W1A, pb, acc);                  // D
    barrier_raw();                           // E: XB[pb] free

    stage_src_lds(aIvw, pb);                 // F: s2(t)
    WAITVM(4);                               // G: own s1 retired (drains prev stores too)
    barrier_raw();                           // H: all s1 visible

    gemm_src(W1B, pb ^ 1, acc);              // I
    WAITVM(0);                               // J: own s2 retired
    barrier_raw();                           // K: all s2 visible; XB[pb^1] free

    stage_src_lds(&aIvu[tb][0], pb ^ 1);     // L: s0(t+1)
    gemm_src(W1C, pb, acc);                  // M

    // N: geom (exact f32) + bias + silu -> hl
#pragma unroll
    for (int rt = 0; rt < 4; ++rt)
#pragma unroll
      for (int j = 0; j < 4; ++j) {
        const float4 g4 = *reinterpret_cast<const float4*>(&geomF[rt * 16 + rowh + j][0]);
#pragma unroll
        for (int ct = 0; ct < 2; ++ct)
          acc[rt][ct][j] += g4.x * w1dv[0][ct] + g4.y * w1dv[1][ct] +
                            g4.z * w1dv[2][ct] + g4.w * w1dv[3][ct];
      }
#pragma unroll
    for (int rt = 0; rt < 4; ++rt)
#pragma unroll
      for (int ct = 0; ct < 2; ++ct) {
        const float bb = b1v[ct];
#pragma unroll
        for (int j = 0; j < 4; ++j) {
          float v = acc[rt][ct][j] + bb;
          v = v * __builtin_amdgcn_rcpf(1.f + __expf(-v));
          hl[(rt * 16 + rowh + j) * HSTR + n0 + ct * 16] = cvt1_pk(v);
        }
      }
    LGKM0();
    barrier_raw();                           // hl visible; geomF/aIuw/aIvw consumed

    // O: aux for next tiles
    {
      int tA = (tt + G < NTILES) ? tt + G : NTILES - 1;
      int tB = (tt + 2 * G < NTILES) ? tt + 2 * G : NTILES - 1;
      stage_aux(tA, tB, tb ^ 1);
    }

    // P: GEMM2 (hl + reg W2 only)
    f32x4 acc2[4][2] = {};
#pragma unroll
    for (int ks = 0; ks < 4; ++ks) {
      bf16x8 a[4];
#pragma unroll
      for (int rt = 0; rt < 4; ++rt)
        a[rt] = *reinterpret_cast<const bf16x8*>(&hl[(rt * 16 + lr) * HSTR + ks * 32 + lk]);
#pragma unroll
      for (int rt = 0; rt < 4; ++rt)
#pragma unroll
        for (int ct = 0; ct < 2; ++ct)
          acc2[rt][ct] = MFMA16(a[rt], w2f[ks][ct], acc2[rt][ct]);
    }

    // Q: pack adjacent cols via shfl, 16 unconditional dword stores (rows < NPAD always)
#pragma unroll
    for (int rt = 0; rt < 4; ++rt)
#pragma unroll
      for (int j = 0; j < 4; ++j) {
        float v0 = acc2[rt][0][j] + b2v[0];
        float v1 = acc2[rt][1][j] + b2v[1];
        float x0 = __shfl_xor(v0, 1);
        float x1 = __shfl_xor(v1, 1);
        const bool even = (l & 1) == 0;
        float lo = even ? v0 : x1;
        float hi = even ? x0 : v1;
        const int dcol = even ? (n0 >> 1) : ((n0 + 15) >> 1);
        u32 pk;
        asm("v_cvt_pk_bf16_f32 %0, %1, %2" : "=v"(pk) : "v"(lo), "v"(hi));
        const int row = t0 + rt * 16 + rowh + j;
        M32[(size_t)row * 64 + dcol] = pk;
      }

    // Z: own s0(t+1)+aux retired, stores left in flight; then all-visible
    WAITVM(16);
    barrier_raw();
    pb ^= 1; tb ^= 1;
  }
  WAITVM(0);
}

// ================= pair kernel with pull-aggregation =================
__global__ __launch_bounds__(256, 3) void k_pair_pull(
    const float* __restrict__ h_pair, const u16* __restrict__ H,
    const u32* __restrict__ M32, const int* __restrict__ start,
    const u16* __restrict__ PW1T, const u16* __restrict__ PW2T,
    const float* __restrict__ b1, const float* __restrict__ b2,
    float* __restrict__ out) {
  __shared__ __align__(16) u16 xl[64 * X2STR];
  __shared__ __align__(16) u16 hl[64 * HSTR];

  const int tid = threadIdx.x;
  const int r0 = blockIdx.x * 64;

  // stage H half
  {
    const int row = tid >> 2, q = tid & 3;
    int rc = r0 + row; rc = (rc < NP) ? rc : (NP - 1);
    const u16x8* sh = reinterpret_cast<const u16x8*>(H + (size_t)rc * 128 + q * 32);
    u16x8* d1 = reinterpret_cast<u16x8*>(&xl[row * X2STR + q * 32]);
#pragma unroll
    for (int i = 0; i < 4; ++i) d1[i] = sh[i];
  }

  const int w = tid >> 6, l = tid & 63;
  u32* xl32 = reinterpret_cast<u32*>(xl);

  // pull agg: wave w owns pairs r0+w*16 .. +15; lane l owns cols 2l,2l+1
  for (int i = 0; i < 16; ++i) {
    int p = r0 + w * 16 + i;
    int pc = (p < NP) ? p : (NP - 1);
    const int s = start[pc], e = start[pc + 1];
    float lo = 0.f, hi = 0.f;
    for (int r = s; r < e; ++r) {
      u32 d = M32[(size_t)r * 64 + l];
      lo += bflo(d);
      hi += bfhi(d);
    }
    u32 pk;
    asm("v_cvt_pk_bf16_f32 %0, %1, %2" : "=v"(pk) : "v"(lo), "v"(hi));
    xl32[(w * 16 + i) * (X2STR / 2) + 64 + l] = pk;
  }
  __syncthreads();

  const int lr = l & 15;
  const int lk = (l >> 4) << 3;
  const int n0 = w * 32 + lr;
  const int rowh = (l >> 4) << 2;

  f32x4 acc[4][2] = {};
#pragma unroll 1
  for (int ks = 0; ks < 8; ++ks) {
    const int k0 = ks * 32;
    bf16x8 a[4], b[2];
#pragma unroll
    for (int rt = 0; rt < 4; ++rt)
      a[rt] = *reinterpret_cast<const bf16x8*>(&xl[(rt * 16 + lr) * X2STR + k0 + lk]);
#pragma unroll
    for (int ct = 0; ct < 2; ++ct)
      b[ct] = *reinterpret_cast<const bf16x8*>(&PW1T[(size_t)(n0 + ct * 16) * 256 + k0 + lk]);
#pragma unroll
    for (int rt = 0; rt < 4; ++rt)
#pragma unroll
      for (int ct = 0; ct < 2; ++ct)
        acc[rt][ct] = MFMA16(a[rt], b[ct], acc[rt][ct]);
  }

  {
    const float b1v0 = b1[n0], b1v1 = b1[n0 + 16];
#pragma unroll
    for (int rt = 0; rt < 4; ++rt)
#pragma unroll
      for (int ct = 0; ct < 2; ++ct) {
        const float bb = ct ? b1v1 : b1v0;
#pragma unroll
        for (int j = 0; j < 4; ++j) {
          float v = acc[rt][ct][j] + bb;
          v = v * __builtin_amdgcn_rcpf(1.f + __expf(-v));
          hl[(rt * 16 + rowh + j) * HSTR + n0 + ct * 16] = cvt1_pk(v);
        }
      }
  }
  __syncthreads();

  f32x4 acc2[4][2] = {};
#pragma unroll
  for (int ks = 0; ks < 4; ++ks) {
    const int k0 = ks * 32;
    bf16x8 a[4], b[2];
#pragma unroll
    for (int rt = 0; rt < 4; ++rt)
      a[rt] = *reinterpret_cast<const bf16x8*>(&hl[(rt * 16 + lr) * HSTR + k0 + lk]);
#pragma unroll
    for (int ct = 0; ct < 2; ++ct)
      b[ct] = *reinterpret_cast<const bf16x8*>(&PW2T[(size_t)(n0 + ct * 16) * 128 + k0 + lk]);
#pragma unroll
    for (int rt = 0; rt < 4; ++rt)
#pragma unroll
      for (int ct = 0; ct < 2; ++ct)
        acc2[rt][ct] = MFMA16(a[rt], b[ct], acc2[rt][ct]);
  }

  {
    const float b2v0 = b2[n0], b2v1 = b2[n0 + 16];
#pragma unroll
    for (int rt = 0; rt < 4; ++rt)
#pragma unroll
      for (int j = 0; j < 4; ++j) {
        const int row = rt * 16 + rowh + j;
        const int r = r0 + row;
        if (r < NP) {
          out[(size_t)r * 128 + n0]      = h_pair[(size_t)r * 128 + n0]      + acc2[rt][0][j] + b2v0;
          out[(size_t)r * 128 + n0 + 16] = h_pair[(size_t)r * 128 + n0 + 16] + acc2[rt][1][j] + b2v1;
        }
      }
  }
}

// ================= MID PATH: R2-exact triplet kernel (proven 224 us) =================
__global__ __launch_bounds__(256, 3) void k_triplet_fast(
    const u16* __restrict__ H,
    const int* __restrict__ ivu, const int* __restrict__ iuw, const int* __restrict__ ivw,
    const float* __restrict__ geom,
    const u16* __restrict__ W1A, const u16* __restrict__ W1B, const u16* __restrict__ W1C,
    const float* __restrict__ w1dF, const u16* __restrict__ W2T,
    const float* __restrict__ b1, const float* __restrict__ b2,
    u16* __restrict__ AGG) {
  __shared__ __align__(16) u16 XB[2][16 * GSTR];
  __shared__ __align__(16) u16 hl[64 * HSTR];
  __shared__ __align__(16) float geomF[2][64][4];
  __shared__ int svw[2][64];

  const int tid = threadIdx.x;
  const int w = tid >> 6, l = tid & 63;
  const int lr = l & 15;
  const int lk = (l >> 4) << 3;
  const int n0 = w * 32 + lr;
  const int rowh = (l >> 4) << 2;
  const int srow = l >> 4;
  const int schunk = (l & 15) ^ ((l >> 4) << 1);

  bf16x8 w2f[4][2];
#pragma unroll
  for (int ks = 0; ks < 4; ++ks)
#pragma unroll
    for (int ct = 0; ct < 2; ++ct)
      w2f[ks][ct] = *reinterpret_cast<const bf16x8*>(&W2T[(size_t)(n0 + ct * 16) * 128 + ks * 32 + lk]);
  const float b1v[2] = {b1[n0], b1[n0 + 16]};
  const float b2v[2] = {b2[n0], b2[n0 + 16]};
  float w1dv[4][2];
#pragma unroll
  for (int k = 0; k < 4; ++k) {
    w1dv[k][0] = w1dF[k * 128 + n0];
    w1dv[k][1] = w1dF[k * 128 + n0 + 16];
  }

  auto stage_src = [&](const int* idxa, int tile, int buf) {
    const int t0 = tile * 64;
#pragma unroll
    for (int q = 0; q < 4; ++q) {
      const int g = w * 4 + q;
      int t = t0 + g * 4 + srow; t = (t < T_TRIP) ? t : (T_TRIP - 1);
      const int idx = idxa[t];
      gload_lds16(H + (size_t)idx * 128 + schunk * 8, &XB[buf][g * GSTR]);
    }
  };

  auto stage_aux = [&](int tile, int tb2) {
    int t = tile * 64 + l; t = (t < T_TRIP) ? t : (T_TRIP - 1);
    if (w == 0) {
      gload_lds16(reinterpret_cast<const u16*>(geom + (size_t)t * 4),
                  reinterpret_cast<u16*>(&geomF[tb2][0][0]));
    } else if (w == 1) {
      gload_lds4(ivw + t, &svw[tb2][0]);
    }
  };

  auto gemm_src = [&](const u16* WT, int buf, f32x4 (&acc)[4][2]) {
#pragma unroll
    for (int ks = 0; ks < 4; ++ks) {
      bf16x8 a[4], b[2];
#pragma unroll
      for (int rt = 0; rt < 4; ++rt) {
        const int r = rt * 16 + lr;
        const int g = r >> 2, s = r & 3;
        const int j = ks * 4 + (l >> 4);
        a[rt] = *reinterpret_cast<const bf16x8*>(&XB[buf][g * GSTR + s * 128 + ((j ^ (s << 1)) << 3)]);
      }
#pragma unroll
      for (int ct = 0; ct < 2; ++ct)
        b[ct] = *reinterpret_cast<const bf16x8*>(&WT[(size_t)(n0 + ct * 16) * 128 + ks * 32 + lk]);
#pragma unroll
      for (int rt = 0; rt < 4; ++rt)
#pragma unroll
        for (int ct = 0; ct < 2; ++ct)
          acc[rt][ct] = MFMA16(a[rt], b[ct], acc[rt][ct]);
    }
  };

  int pb = 0, tb = 0;
  int tt = blockIdx.x;
  stage_src(ivu, tt, 0);

  for (; tt < NTILES; tt += gridDim.x) {
    const int t0 = tt * 64;
    int ttn = tt + gridDim.x; if (ttn >= NTILES) ttn = tt;

    stage_src(iuw, tt, pb ^ 1);
    stage_aux(tt, tb);
    WAITVM(4);
    barrier_raw();

    f32x4 acc[4][2] = {};
    gemm_src(W1A, pb, acc);
    barrier_raw();

    stage_src(ivw, tt, pb);
    WAITVM(4);
    barrier_raw();

    gemm_src(W1B, pb ^ 1, acc);
    WAITVM(0);
    barrier_raw();

    stage_src(ivu, ttn, pb ^ 1);
    gemm_src(W1C, pb, acc);

#pragma unroll
    for (int rt = 0; rt < 4; ++rt)
#pragma unroll
      for (int j = 0; j < 4; ++j) {
        const float4 g4 = *reinterpret_cast<const float4*>(&geomF[tb][rt * 16 + rowh + j][0]);
#pragma unroll
        for (int ct = 0; ct < 2; ++ct)
          acc[rt][ct][j] += g4.x * w1dv[0][ct] + g4.y * w1dv[1][ct] +
                            g4.z * w1dv[2][ct] + g4.w * w1dv[3][ct];
      }
#pragma unroll
    for (int rt = 0; rt < 4; ++rt)
#pragma unroll
      for (int ct = 0; ct < 2; ++ct) {
        const float bb = b1v[ct];
#pragma unroll
        for (int j = 0; j < 4; ++j) {
          float v = acc[rt][ct][j] + bb;
          v = v * __builtin_amdgcn_rcpf(1.f + __expf(-v));
          hl[(rt * 16 + rowh + j) * HSTR + n0 + ct * 16] = cvt1_pk(v);
        }
      }
    LGKM0();
    barrier_raw();

    {
      int tn = tt + gridDim.x; if (tn >= NTILES) tn = tt;
      stage_aux(tn, tb ^ 1);
    }

    f32x4 acc2[4][2] = {};
#pragma unroll
    for (int ks = 0; ks < 4; ++ks) {
      bf16x8 a[4];
#pragma unroll
      for (int rt = 0; rt < 4; ++rt)
        a[rt] = *reinterpret_cast<const bf16x8*>(&hl[(rt * 16 + lr) * HSTR + ks * 32 + lk]);
#pragma unroll
      for (int rt = 0; rt < 4; ++rt)
#pragma unroll
        for (int ct = 0; ct < 2; ++ct)
          acc2[rt][ct] = MFMA16(a[rt], w2f[ks][ct], acc2[rt][ct]);
    }

#pragma unroll
    for (int rt = 0; rt < 4; ++rt) {
      const int4 d4 = *reinterpret_cast<const int4*>(&svw[tb][rt * 16 + rowh]);
#pragma unroll
      for (int j = 0; j < 4; ++j) {
        const int dst = (&d4.x)[j];
        const int trow = t0 + rt * 16 + rowh + j;
        float v0 = acc2[rt][0][j] + b2v[0];
        float v1 = acc2[rt][1][j] + b2v[1];
        float x0 = __shfl_xor(v0, 1);
        float x1 = __shfl_xor(v1, 1);
        const bool even = (l & 1) == 0;
        float lo = even ? v0 : x1;
        float hi = even ? x0 : v1;
        const int col = even ? n0 : (n0 + 15);
        if (trow < T_TRIP) {
          u16* p = AGG + (size_t)dst * 128 + col;
          u32 pk;
          asm("v_cvt_pk_bf16_f32 %0, %1, %2" : "=v"(pk) : "v"(lo), "v"(hi));
          asm volatile("global_atomic_pk_add_bf16 %0, %1, off" :: "v"(p), "v"(pk) : "memory");
        }
      }
    }
    pb ^= 1; tb ^= 1;
  }
  WAITVM(0);
}

__global__ __launch_bounds__(256, 3) void k_pair_fast(
    const float* __restrict__ h_pair, const u16* __restrict__ H, const u16* __restrict__ AGG,
    const u16* __restrict__ PW1T, const u16* __restrict__ PW2T,
    const float* __restrict__ b1, const float* __restrict__ b2,
    float* __restrict__ out) {
  __shared__ __align__(16) u16 xl[64 * X2STR];
  __shared__ __align__(16) u16 hl[64 * HSTR];

  const int tid = threadIdx.x;
  const int r0 = blockIdx.x * 64;

  {
    const int row = tid >> 2, q = tid & 3;
    int rc = r0 + row; rc = (rc < NP) ? rc : (NP - 1);
    const u16x8* sh = reinterpret_cast<const u16x8*>(H + (size_t)rc * 128 + q * 32);
    const u16x8* sa = reinterpret_cast<const u16x8*>(AGG + (size_t)rc * 128 + q * 32);
    u16x8* d1 = reinterpret_cast<u16x8*>(&xl[row * X2STR + q * 32]);
    u16x8* d2 = reinterpret_cast<u16x8*>(&xl[row * X2STR + 128 + q * 32]);
#pragma unroll
    for (int i = 0; i < 4; ++i) { d1[i] = sh[i]; d2[i] = sa[i]; }
  }
  __syncthreads();

  const int w = tid >> 6, l = tid & 63;
  const int lr = l & 15;
  const int lk = (l >> 4) << 3;
  const int n0 = w * 32 + lr;
  const int rowh = (l >> 4) << 2;

  f32x4 acc[4][2] = {};
#pragma unroll 1
  for (int ks = 0; ks < 8; ++ks) {
    const int k0 = ks * 32;
    bf16x8 a[4], b[2];
#pragma unroll
    for (int rt = 0; rt < 4; ++rt)
      a[rt] = *reinterpret_cast<const bf16x8*>(&xl[(rt * 16 + lr) * X2STR + k0 + lk]);
#pragma unroll
    for (int ct = 0; ct < 2; ++ct)
      b[ct] = *reinterpret_cast<const bf16x8*>(&PW1T[(size_t)(n0 + ct * 16) * 256 + k0 + lk]);
#pragma unroll
    for (int rt = 0; rt < 4; ++rt)
#pragma unroll
      for (int ct = 0; ct < 2; ++ct)
        acc[rt][ct] = MFMA16(a[rt], b[ct], acc[rt][ct]);
  }

  {
    const float b1v0 = b1[n0], b1v1 = b1[n0 + 16];
#pragma unroll
    for (int rt = 0; rt < 4; ++rt)
#pragma unroll
      for (int ct = 0; ct < 2; ++ct) {
        const float bb = ct ? b1v1 : b1v0;
#pragma unroll
        for (int j = 0; j < 4; ++j) {
          float v = acc[rt][ct][j] + bb;
          v = v * __builtin_amdgcn_rcpf(1.f + __expf(-v));
          hl[(rt * 16 + rowh + j) * HSTR + n0 + ct * 16] = cvt1_pk(v);
        }
      }
  }
  __syncthreads();

  f32x4 acc2[4][2] = {};
#pragma unroll
  for (int ks = 0; ks < 4; ++ks) {
    const int k0 = ks * 32;
    bf16x8 a[4], b[2];
#pragma unroll
    for (int rt = 0; rt < 4; ++rt)
      a[rt] = *reinterpret_cast<const bf16x8*>(&hl[(rt * 16 + lr) * HSTR + k0 + lk]);
#pragma unroll
    for (int ct = 0; ct < 2; ++ct)
      b[ct] = *reinterpret_cast<const bf16x8*>(&PW2T[(size_t)(n0 + ct * 16) * 128 + k0 + lk]);
#pragma unroll
    for (int rt = 0; rt < 4; ++rt)
#pragma unroll
      for (int ct = 0; ct < 2; ++ct)
        acc2[rt][ct] = MFMA16(a[rt], b[ct], acc2[rt][ct]);
  }

  {
    const float b2v0 = b2[n0], b2v1 = b2[n0 + 16];
#pragma unroll
    for (int rt = 0; rt < 4; ++rt)
#pragma unroll
      for (int j = 0; j < 4; ++j) {
        const int row = rt * 16 + rowh + j;
        const int r = r0 + row;
        if (r < NP) {
          out[(size_t)r * 128 + n0]      = h_pair[(size_t)r * 128 + n0]      + acc2[rt][0][j] + b2v0;
          out[(size_t)r * 128 + n0 + 16] = h_pair[(size_t)r * 128 + n0 + 16] + acc2[rt][1][j] + b2v1;
        }
      }
  }
}

// ===================== R0 fallback (tiny ws) =====================
#define PSI_W1T_OFF 0
#define PSI_W2T_OFF 53248
#define PHI_W1T_OFF 69632
#define PHI_W2T_OFF 102400
#define WS_U16_TOTAL 118784
#define XSTR 424

__global__ void k_prep(const float* __restrict__ psi_w1, const float* __restrict__ psi_w2,
                       const float* __restrict__ phi_w1, const float* __restrict__ phi_w2,
                       u16* __restrict__ ws) {
  int i = blockIdx.x * 256 + threadIdx.x;
  if (i < 128 * 416) {
    int n = i / 416, k = i % 416;
    ws[PSI_W1T_OFF + i] = f2bf(k < 388 ? psi_w1[k * 128 + n] : 0.f);
    return;
  }
  i -= 128 * 416;
  if (i < 128 * 128) {
    int n = i / 128, k = i % 128;
    ws[PSI_W2T_OFF + i] = f2bf(psi_w2[k * 128 + n]);
    return;
  }
  i -= 128 * 128;
  if (i < 128 * 256) {
    int n = i / 256, k = i % 256;
    ws[PHI_W1T_OFF + i] = f2bf(phi_w1[k * 128 + n]);
    return;
  }
  i -= 128 * 256;
  if (i < 128 * 128) {
    int n = i / 128, k = i % 128;
    ws[PHI_W2T_OFF + i] = f2bf(phi_w2[k * 128 + n]);
  }
}

__global__ __launch_bounds__(256, 2) void k_triplet(
    const float* __restrict__ h_pair,
    const int* __restrict__ ivu, const int* __restrict__ iuw, const int* __restrict__ ivw,
    const float* __restrict__ geom,
    const u16* __restrict__ W1T, const u16* __restrict__ W2T,
    const float* __restrict__ b1, const float* __restrict__ b2,
    float* __restrict__ agg) {
  __shared__ __align__(16) u16 xl[64 * XSTR];
  __shared__ __align__(16) u16 hl[64 * HSTR];
  __shared__ int svw[64];

  const int tid = threadIdx.x;
  const int t0 = blockIdx.x * 64;

  {
    const int row = tid >> 2, q = tid & 3;
    const int t = t0 + row;
    const int tc = (t < T_TRIP) ? t : (T_TRIP - 1);
    if (q == 0) svw[row] = (t < T_TRIP) ? ivw[tc] : -1;
    int idx[3];
    idx[0] = ivu[tc]; idx[1] = iuw[tc]; idx[2] = ivw[tc];
#pragma unroll
    for (int s = 0; s < 3; ++s) {
      const float4* src = reinterpret_cast<const float4*>(h_pair + (size_t)idx[s] * 128 + q * 32);
      u16* dst = &xl[row * XSTR + s * 128 + q * 32];
#pragma unroll
      for (int i = 0; i < 8; ++i)
        *reinterpret_cast<ushort4*>(dst + i * 4) = cvt4(src[i]);
    }
  }
  if (tid < 64) {
    const int t = t0 + tid;
    const int tc = (t < T_TRIP) ? t : (T_TRIP - 1);
    const float4 g = reinterpret_cast<const float4*>(geom)[tc];
    u16* dst = &xl[tid * XSTR + 384];
    *reinterpret_cast<ushort4*>(dst) = cvt4(g);
    ushort4 z = {0, 0, 0, 0};
#pragma unroll
    for (int i = 1; i < 8; ++i) *reinterpret_cast<ushort4*>(dst + i * 4) = z;
  }
  __syncthreads();

  const int w = tid >> 6;
  const int l = tid & 63;
  const int lr = l & 15;
  const int lk = (l >> 4) << 3;
  const int n0 = w * 32 + lr;
  const int rowh = (l >> 4) << 2;

  f32x4 acc[4][2] = {};
#pragma unroll 1
  for (int ks = 0; ks < 13; ++ks) {
    const int k0 = ks * 32;
    bf16x8 a[4], b[2];
#pragma unroll
    for (int rt = 0; rt < 4; ++rt)
      a[rt] = *reinterpret_cast<const bf16x8*>(&xl[(rt * 16 + lr) * XSTR + k0 + lk]);
#pragma unroll
    for (int ct = 0; ct < 2; ++ct)
      b[ct] = *reinterpret_cast<const bf16x8*>(&W1T[(size_t)(n0 + ct * 16) * 416 + k0 + lk]);
#pragma unroll
    for (int rt = 0; rt < 4; ++rt)
#pragma unroll
      for (int ct = 0; ct < 2; ++ct)
        acc[rt][ct] = MFMA16(a[rt], b[ct], acc[rt][ct]);
  }

  {
    const float b1v0 = b1[n0], b1v1 = b1[n0 + 16];
#pragma unroll
    for (int rt = 0; rt < 4; ++rt)
#pragma unroll
      for (int ct = 0; ct < 2; ++ct) {
        const float bb = ct ? b1v1 : b1v0;
#pragma unroll
        for (int j = 0; j < 4; ++j) {
          float v = acc[rt][ct][j] + bb;
          v = v / (1.f + __expf(-v));
          hl[(rt * 16 + rowh + j) * HSTR + n0 + ct * 16] = f2bf(v);
        }
      }
  }
  __syncthreads();

  f32x4 acc2[4][2] = {};
#pragma unroll
  for (int ks = 0; ks < 4; ++ks) {
    const int k0 = ks * 32;
    bf16x8 a[4], b[2];
#pragma unroll
    for (int rt = 0; rt < 4; ++rt)
      a[rt] = *reinterpret_cast<const bf16x8*>(&hl[(rt * 16 + lr) * HSTR + k0 + lk]);
#pragma unroll
    for (int ct = 0; ct < 2; ++ct)
      b[ct] = *reinterpret_cast<const bf16x8*>(&W2T[(size_t)(n0 + ct * 16) * 128 + k0 + lk]);
#pragma unroll
    for (int rt = 0; rt < 4; ++rt)
#pragma unroll
      for (int ct = 0; ct < 2; ++ct)
        acc2[rt][ct] = MFMA16(a[rt], b[ct], acc2[rt][ct]);
  }

  {
    const float b2v0 = b2[n0], b2v1 = b2[n0 + 16];
#pragma unroll
    for (int rt = 0; rt < 4; ++rt)
#pragma unroll
      for (int j = 0; j < 4; ++j) {
        const int row = rt * 16 + rowh + j;
        const int dst = svw[row];
        if (dst >= 0) {
          unsafeAtomicAdd(&agg[(size_t)dst * 128 + n0], acc2[rt][0][j] + b2v0);
          unsafeAtomicAdd(&agg[(size_t)dst * 128 + n0 + 16], acc2[rt][1][j] + b2v1);
        }
      }
  }
}

__global__ __launch_bounds__(256, 2) void k_pair(
    const float* __restrict__ h_pair,
    const u16* __restrict__ W1T, const u16* __restrict__ W2T,
    const float* __restrict__ b1, const float* __restrict__ b2,
    float* __restrict__ out) {
  __shared__ __align__(16) u16 xl[64 * X2STR];
  __shared__ __align__(16) u16 hl[64 * HSTR];

  const int tid = threadIdx.x;
  const int r0 = blockIdx.x * 64;

  {
    const int row = tid >> 2, q = tid & 3;
    const int r = r0 + row;
    const int rc = (r < NP) ? r : (NP - 1);
    const float4* s1 = reinterpret_cast<const float4*>(h_pair + (size_t)rc * 128 + q * 32);
    const float4* s2 = reinterpret_cast<const float4*>(out + (size_t)rc * 128 + q * 32);
    u16* d1 = &xl[row * X2STR + q * 32];
    u16* d2 = &xl[row * X2STR + 128 + q * 32];
#pragma unroll
    for (int i = 0; i < 8; ++i) {
      *reinterpret_cast<ushort4*>(d1 + i * 4) = cvt4(s1[i]);
      *reinterpret_cast<ushort4*>(d2 + i * 4) = cvt4(s2[i]);
    }
  }
  __syncthreads();

  const int w = tid >> 6;
  const int l = tid & 63;
  const int lr = l & 15;
  const int lk = (l >> 4) << 3;
  const int n0 = w * 32 + lr;
  const int rowh = (l >> 4) << 2;

  f32x4 acc[4][2] = {};
#pragma unroll 1
  for (int ks = 0; ks < 8; ++ks) {
    const int k0 = ks * 32;
    bf16x8 a[4], b[2];
#pragma unroll
    for (int rt = 0; rt < 4; ++rt)
      a[rt] = *reinterpret_cast<const bf16x8*>(&xl[(rt * 16 + lr) * X2STR + k0 + lk]);
#pragma unroll
    for (int ct = 0; ct < 2; ++ct)
      b[ct] = *reinterpret_cast<const bf16x8*>(&W1T[(size_t)(n0 + ct * 16) * 256 + k0 + lk]);
#pragma unroll
    for (int rt = 0; rt < 4; ++rt)
#pragma unroll
      for (int ct = 0; ct < 2; ++ct)
        acc[rt][ct] = MFMA16(a[rt], b[ct], acc[rt][ct]);
  }

  {
    const float b1v0 = b1[n0], b1v1 = b1[n0 + 16];
#pragma unroll
    for (int rt = 0; rt < 4; ++rt)
#pragma unroll
      for (int ct = 0; ct < 2; ++ct) {
        const float bb = ct ? b1v1 : b1v0;
#pragma unroll
        for (int j = 0; j < 4; ++j) {
          float v = acc[rt][ct][j] + bb;
          v = v / (1.f + __expf(-v));
          hl[(rt * 16 + rowh + j) * HSTR + n0 + ct * 16] = f2bf(v);
        }
      }
  }
  __syncthreads();

  f32x4 acc2[4][2] = {};
#pragma unroll
  for (int ks = 0; ks < 4; ++ks) {
    const int k0 = ks * 32;
    bf16x8 a[4], b[2];
#pragma unroll
    for (int rt = 0; rt < 4; ++rt)
      a[rt] = *reinterpret_cast<const bf16x8*>(&hl[(rt * 16 + lr) * HSTR + k0 + lk]);
#pragma unroll
    for (int ct = 0; ct < 2; ++ct)
      b[ct] = *reinterpret_cast<const bf16x8*>(&W2T[(size_t)(n0 + ct * 16) * 128 + k0 + lk]);
#pragma unroll
    for (int rt = 0; rt < 4; ++rt)
#pragma unroll
      for (int ct = 0; ct < 2; ++ct)
        acc2[rt][ct] = MFMA16(a[rt], b[ct], acc2[rt][ct]);
  }

  {
    const float b2v0 = b2[n0], b2v1 = b2[n0 + 16];
#pragma unroll
    for (int rt = 0; rt < 4; ++rt)
#pragma unroll
      for (int j = 0; j < 4; ++j) {
        const int row = rt * 16 + rowh + j;
        const int r = r0 + row;
        if (r < NP) {
          out[(size_t)r * 128 + n0]      = h_pair[(size_t)r * 128 + n0]      + acc2[rt][0][j] + b2v0;
          out[(size_t)r * 128 + n0 + 16] = h_pair[(size_t)r * 128 + n0 + 16] + acc2[rt][1][j] + b2v1;
        }
      }
  }
}

extern "C" void kernel_launch(void* const* d_in, const int* in_sizes, int n_in,
                              void* d_out, int out_size, void* d_ws, size_t ws_size,
                              hipStream_t stream) {
  const float* h_pair = (const float*)d_in[0];
  const int* ivu = (const int*)d_in[1];
  const int* iuw = (const int*)d_in[2];
  const int* ivw = (const int*)d_in[3];
  const float* geom = (const float*)d_in[4];
  const float* psi_w1 = (const float*)d_in[5];
  const float* psi_b1 = (const float*)d_in[6];
  const float* psi_w2 = (const float*)d_in[7];
  const float* psi_b2 = (const float*)d_in[8];
  const float* phi_w1 = (const float*)d_in[9];
  const float* phi_b1 = (const float*)d_in[10];
  const float* phi_w2 = (const float*)d_in[11];
  const float* phi_b2 = (const float*)d_in[12];

  float* out = (float*)d_out;
  u16* ws = (u16*)d_ws;
  char* wsb = (char*)d_ws;

  if (ws_size >= WS_SORT_BYTES) {
    // ---------- sorted path: no atomic scatter ----------
    u32*  M32    = (u32*)(wsb + FP_M_BYTE);
    int*  cnt    = (int*)(wsb + SB_CNT);
    int*  start  = (int*)(wsb + SB_START);
    int*  cursor = (int*)(wsb + SB_CURSOR);
    int*  bsum   = (int*)(wsb + SB_BSUM);
    int*  ivu_s  = (int*)(wsb + SB_IVU);
    int*  iuw_s  = (int*)(wsb + SB_IUW);
    int*  ivw_s  = (int*)(wsb + SB_IVW);
    float4* geom_s = (float4*)(wsb + SB_GEOM);

    k_prep_fast<<<450, 256, 0, stream>>>(psi_w1, psi_w2, phi_w1, phi_w2, ws);
    k_hconv2<<<6250, 256, 0, stream>>>(h_pair, ws + FP_H);
    hipMemsetAsync(cnt, 0, NP * sizeof(int), stream);
    k_hist<<<(T_TRIP + 255) / 256, 256, 0, stream>>>(ivw, cnt);
    k_scan1<<<98, 1024, 0, stream>>>(cnt, start, bsum);
    k_scan2<<<1, 128, 0, stream>>>(bsum);
    k_scan3<<<(NP + 255) / 256, 256, 0, stream>>>(bsum, start, cursor);
    k_perm<<<(NPAD + 255) / 256, 256, 0, stream>>>(ivu, iuw, ivw, geom, cursor,
                                                   ivu_s, iuw_s, ivw_s, geom_s);
    k_triplet_sorted<<<768, 256, 0, stream>>>(
        ws + FP_H, ivu_s, iuw_s, ivw_s, (const float*)geom_s,
        ws + FP_W1A, ws + FP_W1B, ws + FP_W1C,
        reinterpret_cast<const float*>(ws + FP_W1D), ws + FP_W2,
        psi_b1, psi_b2, M32);
    k_pair_pull<<<(NP + 63) / 64, 256, 0, stream>>>(
        h_pair, ws + FP_H, M32, start,
        ws + FP_PW1, ws + FP_PW2, phi_b1, phi_b2, out);
  } else if (ws_size >= WS_NEED_BYTES) {
    // ---------- R2 fast path (proven) ----------
    k_prep_fast<<<450, 256, 0, stream>>>(psi_w1, psi_w2, phi_w1, phi_w2, ws);
    k_hconv<<<6250, 256, 0, stream>>>(h_pair, ws + FP_H, ws + FP_AGG);
    k_triplet_fast<<<768, 256, 0, stream>>>(
        ws + FP_H, ivu, iuw, ivw, geom,
        ws + FP_W1A, ws + FP_W1B, ws + FP_W1C,
        reinterpret_cast<const float*>(ws + FP_W1D), ws + FP_W2,
        psi_b1, psi_b2, ws + FP_AGG);
    k_pair_fast<<<(NP + 63) / 64, 256, 0, stream>>>(
        h_pair, ws + FP_H, ws + FP_AGG,
        ws + FP_PW1, ws + FP_PW2, phi_b1, phi_b2, out);
  } else {
    // ---------- R0 fallback ----------
    hipMemsetAsync(d_out, 0, (size_t)out_size * sizeof(float), stream);
    k_prep<<<(WS_U16_TOTAL + 255) / 256, 256, 0, stream>>>(psi_w1, psi_w2, phi_w1, phi_w2, ws);
    k_triplet<<<(T_TRIP + 63) / 64, 256, 0, stream>>>(
        h_pair, ivu, iuw, ivw, geom,
        ws + PSI_W1T_OFF, ws + PSI_W2T_OFF, psi_b1, psi_b2, out);
    k_pair<<<(NP + 63) / 64, 256, 0, stream>>>(
        h_pair, ws + PHI_W1T_OFF, ws + PHI_W2T_OFF, phi_b1, phi_b2, out);
  }
}

// Round 5
// 376.346 us; speedup vs baseline: 1.0860x; 1.0860x over previous
//
#include <hip/hip_runtime.h>
#include <hip/hip_bf16.h>

#define T_TRIP 500000
#define NP     100000
#define NTILES 7813    // ceil(T_TRIP/64)
#define NPAD   500032  // NTILES*64

typedef float f32x4 __attribute__((ext_vector_type(4)));
typedef __bf16 bf16x8 __attribute__((ext_vector_type(8)));
typedef unsigned short u16;
typedef unsigned short u16x8 __attribute__((ext_vector_type(8)));
typedef unsigned int u32;

__device__ __forceinline__ u16 f2bf(float f) {
  union { float f; unsigned u; } v; v.f = f;
  unsigned r = v.u + 0x7fffu + ((v.u >> 16) & 1u);
  return (u16)(r >> 16);
}

__device__ __forceinline__ ushort4 cvt4(float4 v) {
  ushort4 o; o.x = f2bf(v.x); o.y = f2bf(v.y); o.z = f2bf(v.z); o.w = f2bf(v.w);
  return o;
}

__device__ __forceinline__ u16 cvt1_pk(float v) {
  unsigned r;
  asm("v_cvt_pk_bf16_f32 %0, %1, %1" : "=v"(r) : "v"(v));
  return (u16)r;
}

__device__ __forceinline__ float bflo(u32 d) {
  union { u32 u; float f; } v; v.u = d << 16; return v.f;
}
__device__ __forceinline__ float bfhi(u32 d) {
  union { u32 u; float f; } v; v.u = d & 0xffff0000u; return v.f;
}

#define MFMA16(a, b, c) __builtin_amdgcn_mfma_f32_16x16x32_bf16((a), (b), (c), 0, 0, 0)

#define WAITVM(N) asm volatile("s_waitcnt vmcnt(" #N ")" ::: "memory")
#define LGKM0()   asm volatile("s_waitcnt lgkmcnt(0)" ::: "memory")

__device__ __forceinline__ void barrier_raw() {
  asm volatile("" ::: "memory");
  __builtin_amdgcn_s_barrier();
  asm volatile("" ::: "memory");
  __builtin_amdgcn_sched_barrier(0);
}

__device__ __forceinline__ void gload_lds16(const u16* g, u16* l) {
  __builtin_amdgcn_global_load_lds((const __attribute__((address_space(1))) void*)g,
                                   (__attribute__((address_space(3))) void*)l, 16, 0, 0);
}
__device__ __forceinline__ void gload_lds4(const int* g, int* l) {
  __builtin_amdgcn_global_load_lds((const __attribute__((address_space(1))) void*)g,
                                   (__attribute__((address_space(3))) void*)l, 4, 0, 0);
}

// =================== ws layout ===================
// u16-element offsets for weights/H/AGG:
#define FP_W1A   0u
#define FP_W1B   16384u
#define FP_W1C   32768u
#define FP_W2    49152u
#define FP_PW1   65536u
#define FP_PW2   98304u
#define FP_W1D   114688u    // f32 [4][128]
#define FP_H     131072u    // h_pair bf16 [NP][128]
#define FP_AGG   12931072u  // agg bf16 [NP][128]
// sorted-path byte offsets:
#define SB_CNT2    51462144ull
#define SB_CURSOR2 51862144ull
#define SB_BSUM2   52262144ull
#define SB_TRIP    52262656ull          // 32B AoS per triplet, NPAD entries
#define WS_S2      68263680ull

#define HSTR   136   // pair-kernel hidden stride (u16)
#define HSTR2  132   // triplet hidden/m stride (u16); 66 dwords == 2 mod 32
#define GSTR   520   // XB group stride (u16)
#define X2STR  264   // pair-input tile stride (u16)

// ---------------- fused pre: weights + hconv/aggzero + hist ----------------
__global__ void k_pre(const float* __restrict__ psi_w1, const float* __restrict__ psi_w2,
                      const float* __restrict__ phi_w1, const float* __restrict__ phi_w2,
                      const float* __restrict__ h, const int* __restrict__ ivw,
                      u16* __restrict__ ws, int* __restrict__ cnt) {
  const int b = blockIdx.x;
  if (b < 450) {                       // ---- weight prep (115200 elems) ----
    int i = b * 256 + threadIdx.x;
    if (i < 49152) {
      int s = i / 16384, r = i % 16384;
      int n = r / 128, k = r % 128;
      ws[FP_W1A + i] = f2bf(psi_w1[(s * 128 + k) * 128 + n]);
      return;
    }
    i -= 49152;
    if (i < 16384) {
      int n = i / 128, k = i % 128;
      ws[FP_W2 + i] = f2bf(psi_w2[k * 128 + n]);
      return;
    }
    i -= 16384;
    if (i < 32768) {
      int n = i / 256, k = i % 256;
      ws[FP_PW1 + i] = f2bf(phi_w1[k * 128 + n]);
      return;
    }
    i -= 32768;
    if (i < 16384) {
      int n = i / 128, k = i % 128;
      ws[FP_PW2 + i] = f2bf(phi_w2[k * 128 + n]);
      return;
    }
    i -= 16384;
    if (i < 512) {
      int k = i / 128, n = i % 128;
      reinterpret_cast<float*>(ws + FP_W1D)[i] = psi_w1[(384 + k) * 128 + n];
    }
  } else if (b < 6700) {               // ---- h->bf16 + zero AGG ----
    const size_t i = (size_t)((b - 450) * 256 + threadIdx.x) * 8;
    float4 v0 = *reinterpret_cast<const float4*>(h + i);
    float4 v1 = *reinterpret_cast<const float4*>(h + i + 4);
    *reinterpret_cast<ushort4*>(ws + FP_H + i)     = cvt4(v0);
    *reinterpret_cast<ushort4*>(ws + FP_H + i + 4) = cvt4(v1);
    ushort4 z = {0, 0, 0, 0};
    *reinterpret_cast<ushort4*>(ws + FP_AGG + i)     = z;
    *reinterpret_cast<ushort4*>(ws + FP_AGG + i + 4) = z;
  } else {                             // ---- histogram ----
    int i = (b - 6700) * 256 + threadIdx.x;
    if (i < T_TRIP) atomicAdd(&cnt[ivw[i]], 1);
  }
}

// ================= scan =================
__global__ __launch_bounds__(1024) void k_scan1(const int* __restrict__ cnt,
                                                int* __restrict__ cursor, int* __restrict__ bsum) {
  __shared__ int wsum[16];
  const int idx = blockIdx.x * 1024 + threadIdx.x;
  const int lane = threadIdx.x & 63, wid = threadIdx.x >> 6;
  int v = (idx < NP) ? cnt[idx] : 0;
  int x = v;
#pragma unroll
  for (int off = 1; off < 64; off <<= 1) {
    int n = __shfl_up(x, off);
    if (lane >= off) x += n;
  }
  if (lane == 63) wsum[wid] = x;
  __syncthreads();
  if (threadIdx.x < 16) {
    int s = wsum[threadIdx.x];
#pragma unroll
    for (int off = 1; off < 16; off <<= 1) {
      int n = __shfl_up(s, off);
      if (threadIdx.x >= off) s += n;
    }
    wsum[threadIdx.x] = s;
  }
  __syncthreads();
  const int base = wid ? wsum[wid - 1] : 0;
  if (idx < NP) cursor[idx] = base + x - v;      // exclusive within block
  if (threadIdx.x == 1023) bsum[blockIdx.x] = base + x;
}

__global__ void k_scan2(int* __restrict__ bsum) {
  __shared__ int s[128];
  const int t = threadIdx.x;
  int v = (t < 98) ? bsum[t] : 0;
  s[t] = v; __syncthreads();
#pragma unroll
  for (int off = 1; off < 128; off <<= 1) {
    int a = (t >= off) ? s[t - off] : 0;
    __syncthreads();
    s[t] += a;
    __syncthreads();
  }
  if (t < 98) bsum[t] = s[t] - v;
}

__global__ void k_scan3(const int* __restrict__ bsum, int* __restrict__ cursor) {
  int idx = blockIdx.x * 256 + threadIdx.x;
  if (idx < NP) cursor[idx] += bsum[idx >> 10];
}

// ================= permute -> 32B AoS =================
__global__ void k_perm_aos(const int* __restrict__ ivu, const int* __restrict__ iuw,
                           const int* __restrict__ ivw, const float* __restrict__ geom,
                           int* __restrict__ cursor, int4* __restrict__ trip) {
  int i = blockIdx.x * 256 + threadIdx.x;
  if (i < T_TRIP) {
    int v = ivw[i];
    int pos = atomicAdd(&cursor[v], 1);
    int4 hdr; hdr.x = ivu[i]; hdr.y = iuw[i]; hdr.z = v; hdr.w = 0;
    float4 g = reinterpret_cast<const float4*>(geom)[i];
    trip[(size_t)pos * 2] = hdr;
    reinterpret_cast<float4*>(trip)[(size_t)pos * 2 + 1] = g;
  } else if (i < NPAD) {
    int4 z = {0, 0, 0, 0};
    trip[(size_t)i * 2] = z;
    trip[(size_t)i * 2 + 1] = z;
  }
}

// ================= sorted triplet kernel with in-tile segmented aggregation =================
__global__ __launch_bounds__(256, 3) void k_triplet_sortagg(
    const u16* __restrict__ H, const int* __restrict__ trip,
    const u16* __restrict__ W1A, const u16* __restrict__ W1B, const u16* __restrict__ W1C,
    const float* __restrict__ w1dF, const u16* __restrict__ W2T,
    const float* __restrict__ b1, const float* __restrict__ b2,
    u16* __restrict__ AGG) {
  __shared__ __align__(16) u16 XB[2][16 * GSTR];   // 33280 B
  __shared__ __align__(16) u16 hl[64 * HSTR2];     // 16896 B (also m-tile, stride 66 dw)
  __shared__ __align__(16) int aosT[2][512];       //  4096 B   total 54272 B

  u32* mlu = reinterpret_cast<u32*>(hl);

  const int tid = threadIdx.x;
  const int w = tid >> 6, l = tid & 63;
  const int lr = l & 15;
  const int lk = (l >> 4) << 3;
  const int n0 = w * 32 + lr;
  const int rowh = (l >> 4) << 2;
  const int srow = l >> 4;
  const int schunk = (l & 15) ^ ((l >> 4) << 1);

  // hoisted constants (W2 frags in regs)
  bf16x8 w2f[4][2];
#pragma unroll
  for (int ks = 0; ks < 4; ++ks)
#pragma unroll
    for (int ct = 0; ct < 2; ++ct)
      w2f[ks][ct] = *reinterpret_cast<const bf16x8*>(&W2T[(size_t)(n0 + ct * 16) * 128 + ks * 32 + lk]);
  const float b1v[2] = {b1[n0], b1[n0 + 16]};
  const float b2v[2] = {b2[n0], b2[n0 + 16]};
  float w1dv[4][2];
#pragma unroll
  for (int k = 0; k < 4; ++k) {
    w1dv[k][0] = w1dF[k * 128 + n0];
    w1dv[k][1] = w1dF[k * 128 + n0 + 16];
  }

  auto stage_src = [&](int cb, int sel, int buf) {
#pragma unroll
    for (int q = 0; q < 4; ++q) {
      const int g = w * 4 + q;
      const int idx = aosT[cb][(g * 4 + srow) * 8 + sel];   // LDS broadcast
      gload_lds16(H + (size_t)idx * 128 + schunk * 8, &XB[buf][g * GSTR]);
    }
  };

  auto stage_aos = [&](int tile, int cb) {                   // 2 uniform vm-ops per wave
    const int* src = trip + (size_t)tile * 512;
    gload_lds4(src + w * 64 + l,       &aosT[cb][w * 64]);
    gload_lds4(src + 256 + w * 64 + l, &aosT[cb][256 + w * 64]);
  };

  auto gemm_src = [&](const u16* WT, int buf, f32x4 (&acc)[4][2]) {
#pragma unroll
    for (int ks = 0; ks < 4; ++ks) {
      bf16x8 a[4], b[2];
#pragma unroll
      for (int rt = 0; rt < 4; ++rt) {
        const int r = rt * 16 + lr;
        const int g = r >> 2, s = r & 3;
        const int j = ks * 4 + (l >> 4);
        a[rt] = *reinterpret_cast<const bf16x8*>(&XB[buf][g * GSTR + s * 128 + ((j ^ (s << 1)) << 3)]);
      }
#pragma unroll
      for (int ct = 0; ct < 2; ++ct)
        b[ct] = *reinterpret_cast<const bf16x8*>(&WT[(size_t)(n0 + ct * 16) * 128 + ks * 32 + lk]);
#pragma unroll
      for (int rt = 0; rt < 4; ++rt)
#pragma unroll
        for (int ct = 0; ct < 2; ++ct)
          acc[rt][ct] = MFMA16(a[rt], b[ct], acc[rt][ct]);
    }
  };

  int cur = 0, pb = 0;
  int tt = blockIdx.x;
  const int G = gridDim.x;

  // ---- prologue: AoS tiles t and t+G, then s0(t) ----
  {
    int t1 = tt + G; if (t1 >= NTILES) t1 = NTILES - 1;
    stage_aos(tt, 0);
    stage_aos(t1, 1);
    WAITVM(0);
    barrier_raw();
    stage_src(0, 0 /*ivu*/, 0);
  }

  for (; tt < NTILES; tt += G) {
    const int t0 = tt * 64;

    stage_src(cur, 1 /*iuw*/, pb ^ 1);       // A: s1(t)
    WAITVM(4);                               // s0 resident
    barrier_raw();

    f32x4 acc[4][2] = {};
    gemm_src(W1A, pb, acc);                  // D
    barrier_raw();                           // XB[pb] free

    stage_src(cur, 2 /*ivw*/, pb);           // F: s2(t)
    WAITVM(4);                               // s1 resident
    barrier_raw();

    gemm_src(W1B, pb ^ 1, acc);              // I
    WAITVM(0);                               // s2 resident
    barrier_raw();                           // XB[pb^1] free

    stage_src(cur ^ 1, 0 /*ivu*/, pb ^ 1);   // L: s0(t+1)
    gemm_src(W1C, pb, acc);                  // M

    // N: geom (f32 exact, from AoS) + bias + silu -> hl
#pragma unroll
    for (int rt = 0; rt < 4; ++rt)
#pragma unroll
      for (int j = 0; j < 4; ++j) {
        const int row = rt * 16 + rowh + j;
        const float4 g4 = *reinterpret_cast<const float4*>(&aosT[cur][row * 8 + 4]);
#pragma unroll
        for (int ct = 0; ct < 2; ++ct)
          acc[rt][ct][j] += g4.x * w1dv[0][ct] + g4.y * w1dv[1][ct] +
                            g4.z * w1dv[2][ct] + g4.w * w1dv[3][ct];
      }
#pragma unroll
    for (int rt = 0; rt < 4; ++rt)
#pragma unroll
      for (int ct = 0; ct < 2; ++ct) {
        const float bb = b1v[ct];
#pragma unroll
        for (int j = 0; j < 4; ++j) {
          float v = acc[rt][ct][j] + bb;
          v = v * __builtin_amdgcn_rcpf(1.f + __expf(-v));
          hl[(rt * 16 + rowh + j) * HSTR2 + n0 + ct * 16] = cvt1_pk(v);
        }
      }
    LGKM0();
    barrier_raw();

    // P: GEMM2 (hl + reg W2)
    f32x4 acc2[4][2] = {};
#pragma unroll
    for (int ks = 0; ks < 4; ++ks) {
      bf16x8 a[4];
#pragma unroll
      for (int rt = 0; rt < 4; ++rt)
        a[rt] = *reinterpret_cast<const bf16x8*>(&hl[(rt * 16 + lr) * HSTR2 + ks * 32 + lk]);
#pragma unroll
      for (int rt = 0; rt < 4; ++rt)
#pragma unroll
        for (int ct = 0; ct < 2; ++ct)
          acc2[rt][ct] = MFMA16(a[rt], w2f[ks][ct], acc2[rt][ct]);
    }
    barrier_raw();                           // all hl readers done -> reuse as m-tile

    // Q: pack bf16 pairs -> m-tile in LDS (stride 66 dwords)
#pragma unroll
    for (int rt = 0; rt < 4; ++rt)
#pragma unroll
      for (int j = 0; j < 4; ++j) {
        const int row = rt * 16 + rowh + j;
        float v0 = acc2[rt][0][j] + b2v[0];
        float v1 = acc2[rt][1][j] + b2v[1];
        float x0 = __shfl_xor(v0, 1);
        float x1 = __shfl_xor(v1, 1);
        const bool even = (l & 1) == 0;
        float lo = even ? v0 : x1;
        float hi = even ? x0 : v1;
        const int dcol = even ? (n0 >> 1) : ((n0 + 15) >> 1);
        u32 pk;
        asm("v_cvt_pk_bf16_f32 %0, %1, %2" : "=v"(pk) : "v"(lo), "v"(hi));
        mlu[row * 66 + dcol] = pk;
      }
    LGKM0();
    barrier_raw();

    // R: segmented reduce over sorted vw; one pk-atomic per run per packed col
    {
      float lo = 0.f, hi = 0.f;
      int vwc = aosT[cur][(w * 16) * 8 + 2];
#pragma unroll 1
      for (int r8 = 0; r8 < 16; ++r8) {
        const int row = w * 16 + r8;
        const u32 d = mlu[row * 66 + l];
        if (t0 + row < T_TRIP) { lo += bflo(d); hi += bfhi(d); }
        const int vwn = (row < 63) ? aosT[cur][(row + 1) * 8 + 2] : -1;
        if ((r8 == 15) || (vwn != vwc)) {
          u16* p = AGG + (size_t)vwc * 128 + l * 2;
          u32 pk;
          asm("v_cvt_pk_bf16_f32 %0, %1, %2" : "=v"(pk) : "v"(lo), "v"(hi));
          asm volatile("global_atomic_pk_add_bf16 %0, %1, off" :: "v"(p), "v"(pk) : "memory");
          lo = 0.f; hi = 0.f; vwc = vwn;
        }
      }
    }
    barrier_raw();                           // aosT[cur] free

    // O: AoS prefetch tile t+2G into aosT[cur]
    {
      int t2 = tt + 2 * G; if (t2 >= NTILES) t2 = NTILES - 1;
      stage_aos(t2, cur);
    }

    WAITVM(0);                               // Z: drain L + atomics + O
    barrier_raw();
    pb ^= 1; cur ^= 1;
  }
  WAITVM(0);
}

// ================= pair kernel (R2-proven) =================
__global__ __launch_bounds__(256, 3) void k_pair_fast(
    const float* __restrict__ h_pair, const u16* __restrict__ H, const u16* __restrict__ AGG,
    const u16* __restrict__ PW1T, const u16* __restrict__ PW2T,
    const float* __restrict__ b1, const float* __restrict__ b2,
    float* __restrict__ out) {
  __shared__ __align__(16) u16 xl[64 * X2STR];
  __shared__ __align__(16) u16 hl[64 * HSTR];

  const int tid = threadIdx.x;
  const int r0 = blockIdx.x * 64;

  {
    const int row = tid >> 2, q = tid & 3;
    int rc = r0 + row; rc = (rc < NP) ? rc : (NP - 1);
    const u16x8* sh = reinterpret_cast<const u16x8*>(H + (size_t)rc * 128 + q * 32);
    const u16x8* sa = reinterpret_cast<const u16x8*>(AGG + (size_t)rc * 128 + q * 32);
    u16x8* d1 = reinterpret_cast<u16x8*>(&xl[row * X2STR + q * 32]);
    u16x8* d2 = reinterpret_cast<u16x8*>(&xl[row * X2STR + 128 + q * 32]);
#pragma unroll
    for (int i = 0; i < 4; ++i) { d1[i] = sh[i]; d2[i] = sa[i]; }
  }
  __syncthreads();

  const int w = tid >> 6, l = tid & 63;
  const int lr = l & 15;
  const int lk = (l >> 4) << 3;
  const int n0 = w * 32 + lr;
  const int rowh = (l >> 4) << 2;

  f32x4 acc[4][2] = {};
#pragma unroll 1
  for (int ks = 0; ks < 8; ++ks) {
    const int k0 = ks * 32;
    bf16x8 a[4], b[2];
#pragma unroll
    for (int rt = 0; rt < 4; ++rt)
      a[rt] = *reinterpret_cast<const bf16x8*>(&xl[(rt * 16 + lr) * X2STR + k0 + lk]);
#pragma unroll
    for (int ct = 0; ct < 2; ++ct)
      b[ct] = *reinterpret_cast<const bf16x8*>(&PW1T[(size_t)(n0 + ct * 16) * 256 + k0 + lk]);
#pragma unroll
    for (int rt = 0; rt < 4; ++rt)
#pragma unroll
      for (int ct = 0; ct < 2; ++ct)
        acc[rt][ct] = MFMA16(a[rt], b[ct], acc[rt][ct]);
  }

  {
    const float b1v0 = b1[n0], b1v1 = b1[n0 + 16];
#pragma unroll
    for (int rt = 0; rt < 4; ++rt)
#pragma unroll
      for (int ct = 0; ct < 2; ++ct) {
        const float bb = ct ? b1v1 : b1v0;
#pragma unroll
        for (int j = 0; j < 4; ++j) {
          float v = acc[rt][ct][j] + bb;
          v = v * __builtin_amdgcn_rcpf(1.f + __expf(-v));
          hl[(rt * 16 + rowh + j) * HSTR + n0 + ct * 16] = cvt1_pk(v);
        }
      }
  }
  __syncthreads();

  f32x4 acc2[4][2] = {};
#pragma unroll
  for (int ks = 0; ks < 4; ++ks) {
    const int k0 = ks * 32;
    bf16x8 a[4], b[2];
#pragma unroll
    for (int rt = 0; rt < 4; ++rt)
      a[rt] = *reinterpret_cast<const bf16x8*>(&hl[(rt * 16 + lr) * HSTR + k0 + lk]);
#pragma unroll
    for (int ct = 0; ct < 2; ++ct)
      b[ct] = *reinterpret_cast<const bf16x8*>(&PW2T[(size_t)(n0 + ct * 16) * 128 + k0 + lk]);
#pragma unroll
    for (int rt = 0; rt < 4; ++rt)
#pragma unroll
      for (int ct = 0; ct < 2; ++ct)
        acc2[rt][ct] = MFMA16(a[rt], b[ct], acc2[rt][ct]);
  }

  {
    const float b2v0 = b2[n0], b2v1 = b2[n0 + 16];
#pragma unroll
    for (int rt = 0; rt < 4; ++rt)
#pragma unroll
      for (int j = 0; j < 4; ++j) {
        const int row = rt * 16 + rowh + j;
        const int r = r0 + row;
        if (r < NP) {
          out[(size_t)r * 128 + n0]      = h_pair[(size_t)r * 128 + n0]      + acc2[rt][0][j] + b2v0;
          out[(size_t)r * 128 + n0 + 16] = h_pair[(size_t)r * 128 + n0 + 16] + acc2[rt][1][j] + b2v1;
        }
      }
  }
}

// ===================== R0 fallback (tiny ws) =====================
#define PSI_W1T_OFF 0
#define PSI_W2T_OFF 53248
#define PHI_W1T_OFF 69632
#define PHI_W2T_OFF 102400
#define WS_U16_TOTAL 118784
#define XSTR 424

__global__ void k_prep(const float* __restrict__ psi_w1, const float* __restrict__ psi_w2,
                       const float* __restrict__ phi_w1, const float* __restrict__ phi_w2,
                       u16* __restrict__ ws) {
  int i = blockIdx.x * 256 + threadIdx.x;
  if (i < 128 * 416) {
    int n = i / 416, k = i % 416;
    ws[PSI_W1T_OFF + i] = f2bf(k < 388 ? psi_w1[k * 128 + n] : 0.f);
    return;
  }
  i -= 128 * 416;
  if (i < 128 * 128) {
    int n = i / 128, k = i % 128;
    ws[PSI_W2T_OFF + i] = f2bf(psi_w2[k * 128 + n]);
    return;
  }
  i -= 128 * 128;
  if (i < 128 * 256) {
    int n = i / 256, k = i % 256;
    ws[PHI_W1T_OFF + i] = f2bf(phi_w1[k * 128 + n]);
    return;
  }
  i -= 128 * 256;
  if (i < 128 * 128) {
    int n = i / 128, k = i % 128;
    ws[PHI_W2T_OFF + i] = f2bf(phi_w2[k * 128 + n]);
  }
}

__global__ __launch_bounds__(256, 2) void k_triplet(
    const float* __restrict__ h_pair,
    const int* __restrict__ ivu, const int* __restrict__ iuw, const int* __restrict__ ivw,
    const float* __restrict__ geom,
    const u16* __restrict__ W1T, const u16* __restrict__ W2T,
    const float* __restrict__ b1, const float* __restrict__ b2,
    float* __restrict__ agg) {
  __shared__ __align__(16) u16 xl[64 * XSTR];
  __shared__ __align__(16) u16 hl[64 * HSTR];
  __shared__ int svw[64];

  const int tid = threadIdx.x;
  const int t0 = blockIdx.x * 64;

  {
    const int row = tid >> 2, q = tid & 3;
    const int t = t0 + row;
    const int tc = (t < T_TRIP) ? t : (T_TRIP - 1);
    if (q == 0) svw[row] = (t < T_TRIP) ? ivw[tc] : -1;
    int idx[3];
    idx[0] = ivu[tc]; idx[1] = iuw[tc]; idx[2] = ivw[tc];
#pragma unroll
    for (int s = 0; s < 3; ++s) {
      const float4* src = reinterpret_cast<const float4*>(h_pair + (size_t)idx[s] * 128 + q * 32);
      u16* dst = &xl[row * XSTR + s * 128 + q * 32];
#pragma unroll
      for (int i = 0; i < 8; ++i)
        *reinterpret_cast<ushort4*>(dst + i * 4) = cvt4(src[i]);
    }
  }
  if (tid < 64) {
    const int t = t0 + tid;
    const int tc = (t < T_TRIP) ? t : (T_TRIP - 1);
    const float4 g = reinterpret_cast<const float4*>(geom)[tc];
    u16* dst = &xl[tid * XSTR + 384];
    *reinterpret_cast<ushort4*>(dst) = cvt4(g);
    ushort4 z = {0, 0, 0, 0};
#pragma unroll
    for (int i = 1; i < 8; ++i) *reinterpret_cast<ushort4*>(dst + i * 4) = z;
  }
  __syncthreads();

  const int w = tid >> 6;
  const int l = tid & 63;
  const int lr = l & 15;
  const int lk = (l >> 4) << 3;
  const int n0 = w * 32 + lr;
  const int rowh = (l >> 4) << 2;

  f32x4 acc[4][2] = {};
#pragma unroll 1
  for (int ks = 0; ks < 13; ++ks) {
    const int k0 = ks * 32;
    bf16x8 a[4], b[2];
#pragma unroll
    for (int rt = 0; rt < 4; ++rt)
      a[rt] = *reinterpret_cast<const bf16x8*>(&xl[(rt * 16 + lr) * XSTR + k0 + lk]);
#pragma unroll
    for (int ct = 0; ct < 2; ++ct)
      b[ct] = *reinterpret_cast<const bf16x8*>(&W1T[(size_t)(n0 + ct * 16) * 416 + k0 + lk]);
#pragma unroll
    for (int rt = 0; rt < 4; ++rt)
#pragma unroll
      for (int ct = 0; ct < 2; ++ct)
        acc[rt][ct] = MFMA16(a[rt], b[ct], acc[rt][ct]);
  }

  {
    const float b1v0 = b1[n0], b1v1 = b1[n0 + 16];
#pragma unroll
    for (int rt = 0; rt < 4; ++rt)
#pragma unroll
      for (int ct = 0; ct < 2; ++ct) {
        const float bb = ct ? b1v1 : b1v0;
#pragma unroll
        for (int j = 0; j < 4; ++j) {
          float v = acc[rt][ct][j] + bb;
          v = v / (1.f + __expf(-v));
          hl[(rt * 16 + rowh + j) * HSTR + n0 + ct * 16] = f2bf(v);
        }
      }
  }
  __syncthreads();

  f32x4 acc2[4][2] = {};
#pragma unroll
  for (int ks = 0; ks < 4; ++ks) {
    const int k0 = ks * 32;
    bf16x8 a[4], b[2];
#pragma unroll
    for (int rt = 0; rt < 4; ++rt)
      a[rt] = *reinterpret_cast<const bf16x8*>(&hl[(rt * 16 + lr) * HSTR + k0 + lk]);
#pragma unroll
    for (int ct = 0; ct < 2; ++ct)
      b[ct] = *reinterpret_cast<const bf16x8*>(&W2T[(size_t)(n0 + ct * 16) * 128 + k0 + lk]);
#pragma unroll
    for (int rt = 0; rt < 4; ++rt)
#pragma unroll
      for (int ct = 0; ct < 2; ++ct)
        acc2[rt][ct] = MFMA16(a[rt], b[ct], acc2[rt][ct]);
  }

  {
    const float b2v0 = b2[n0], b2v1 = b2[n0 + 16];
#pragma unroll
    for (int rt = 0; rt < 4; ++rt)
#pragma unroll
      for (int j = 0; j < 4; ++j) {
        const int row = rt * 16 + rowh + j;
        const int dst = svw[row];
        if (dst >= 0) {
          unsafeAtomicAdd(&agg[(size_t)dst * 128 + n0], acc2[rt][0][j] + b2v0);
          unsafeAtomicAdd(&agg[(size_t)dst * 128 + n0 + 16], acc2[rt][1][j] + b2v1);
        }
      }
  }
}

__global__ __launch_bounds__(256, 2) void k_pair(
    const float* __restrict__ h_pair,
    const u16* __restrict__ W1T, const u16* __restrict__ W2T,
    const float* __restrict__ b1, const float* __restrict__ b2,
    float* __restrict__ out) {
  __shared__ __align__(16) u16 xl[64 * X2STR];
  __shared__ __align__(16) u16 hl[64 * HSTR];

  const int tid = threadIdx.x;
  const int r0 = blockIdx.x * 64;

  {
    const int row = tid >> 2, q = tid & 3;
    const int r = r0 + row;
    const int rc = (r < NP) ? r : (NP - 1);
    const float4* s1 = reinterpret_cast<const float4*>(h_pair + (size_t)rc * 128 + q * 32);
    const float4* s2 = reinterpret_cast<const float4*>(out + (size_t)rc * 128 + q * 32);
    u16* d1 = &xl[row * X2STR + q * 32];
    u16* d2 = &xl[row * X2STR + 128 + q * 32];
#pragma unroll
    for (int i = 0; i < 8; ++i) {
      *reinterpret_cast<ushort4*>(d1 + i * 4) = cvt4(s1[i]);
      *reinterpret_cast<ushort4*>(d2 + i * 4) = cvt4(s2[i]);
    }
  }
  __syncthreads();

  const int w = tid >> 6;
  const int l = tid & 63;
  const int lr = l & 15;
  const int lk = (l >> 4) << 3;
  const int n0 = w * 32 + lr;
  const int rowh = (l >> 4) << 2;

  f32x4 acc[4][2] = {};
#pragma unroll 1
  for (int ks = 0; ks < 8; ++ks) {
    const int k0 = ks * 32;
    bf16x8 a[4], b[2];
#pragma unroll
    for (int rt = 0; rt < 4; ++rt)
      a[rt] = *reinterpret_cast<const bf16x8*>(&xl[(rt * 16 + lr) * X2STR + k0 + lk]);
#pragma unroll
    for (int ct = 0; ct < 2; ++ct)
      b[ct] = *reinterpret_cast<const bf16x8*>(&W1T[(size_t)(n0 + ct * 16) * 256 + k0 + lk]);
#pragma unroll
    for (int rt = 0; rt < 4; ++rt)
#pragma unroll
      for (int ct = 0; ct < 2; ++ct)
        acc[rt][ct] = MFMA16(a[rt], b[ct], acc[rt][ct]);
  }

  {
    const float b1v0 = b1[n0], b1v1 = b1[n0 + 16];
#pragma unroll
    for (int rt = 0; rt < 4; ++rt)
#pragma unroll
      for (int ct = 0; ct < 2; ++ct) {
        const float bb = ct ? b1v1 : b1v0;
#pragma unroll
        for (int j = 0; j < 4; ++j) {
          float v = acc[rt][ct][j] + bb;
          v = v / (1.f + __expf(-v));
          hl[(rt * 16 + rowh + j) * HSTR + n0 + ct * 16] = f2bf(v);
        }
      }
  }
  __syncthreads();

  f32x4 acc2[4][2] = {};
#pragma unroll
  for (int ks = 0; ks < 4; ++ks) {
    const int k0 = ks * 32;
    bf16x8 a[4], b[2];
#pragma unroll
    for (int rt = 0; rt < 4; ++rt)
      a[rt] = *reinterpret_cast<const bf16x8*>(&hl[(rt * 16 + lr) * HSTR + k0 + lk]);
#pragma unroll
    for (int ct = 0; ct < 2; ++ct)
      b[ct] = *reinterpret_cast<const bf16x8*>(&W2T[(size_t)(n0 + ct * 16) * 128 + k0 + lk]);
#pragma unroll
    for (int rt = 0; rt < 4; ++rt)
#pragma unroll
      for (int ct = 0; ct < 2; ++ct)
        acc2[rt][ct] = MFMA16(a[rt], b[ct], acc2[rt][ct]);
  }

  {
    const float b2v0 = b2[n0], b2v1 = b2[n0 + 16];
#pragma unroll
    for (int rt = 0; rt < 4; ++rt)
#pragma unroll
      for (int j = 0; j < 4; ++j) {
        const int row = rt * 16 + rowh + j;
        const int r = r0 + row;
        if (r < NP) {
          out[(size_t)r * 128 + n0]      = h_pair[(size_t)r * 128 + n0]      + acc2[rt][0][j] + b2v0;
          out[(size_t)r * 128 + n0 + 16] = h_pair[(size_t)r * 128 + n0 + 16] + acc2[rt][1][j] + b2v1;
        }
      }
  }
}

extern "C" void kernel_launch(void* const* d_in, const int* in_sizes, int n_in,
                              void* d_out, int out_size, void* d_ws, size_t ws_size,
                              hipStream_t stream) {
  const float* h_pair = (const float*)d_in[0];
  const int* ivu = (const int*)d_in[1];
  const int* iuw = (const int*)d_in[2];
  const int* ivw = (const int*)d_in[3];
  const float* geom = (const float*)d_in[4];
  const float* psi_w1 = (const float*)d_in[5];
  const float* psi_b1 = (const float*)d_in[6];
  const float* psi_w2 = (const float*)d_in[7];
  const float* psi_b2 = (const float*)d_in[8];
  const float* phi_w1 = (const float*)d_in[9];
  const float* phi_b1 = (const float*)d_in[10];
  const float* phi_w2 = (const float*)d_in[11];
  const float* phi_b2 = (const float*)d_in[12];

  float* out = (float*)d_out;
  u16* ws = (u16*)d_ws;
  char* wsb = (char*)d_ws;

  if (ws_size >= WS_S2) {
    int*  cnt    = (int*)(wsb + SB_CNT2);
    int*  cursor = (int*)(wsb + SB_CURSOR2);
    int*  bsum   = (int*)(wsb + SB_BSUM2);
    int4* trip   = (int4*)(wsb + SB_TRIP);

    hipMemsetAsync(cnt, 0, NP * sizeof(int), stream);
    k_pre<<<8654, 256, 0, stream>>>(psi_w1, psi_w2, phi_w1, phi_w2, h_pair, ivw, ws, cnt);
    k_scan1<<<98, 1024, 0, stream>>>(cnt, cursor, bsum);
    k_scan2<<<1, 128, 0, stream>>>(bsum);
    k_scan3<<<391, 256, 0, stream>>>(bsum, cursor);
    k_perm_aos<<<(NPAD + 255) / 256, 256, 0, stream>>>(ivu, iuw, ivw, geom, cursor, trip);
    k_triplet_sortagg<<<768, 256, 0, stream>>>(
        ws + FP_H, (const int*)trip,
        ws + FP_W1A, ws + FP_W1B, ws + FP_W1C,
        reinterpret_cast<const float*>(ws + FP_W1D), ws + FP_W2,
        psi_b1, psi_b2, ws + FP_AGG);
    k_pair_fast<<<(NP + 63) / 64, 256, 0, stream>>>(
        h_pair, ws + FP_H, ws + FP_AGG,
        ws + FP_PW1, ws + FP_PW2, phi_b1, phi_b2, out);
  } else {
    // ---------- R0 fallback ----------
    hipMemsetAsync(d_out, 0, (size_t)out_size * sizeof(float), stream);
    k_prep<<<(WS_U16_TOTAL + 255) / 256, 256, 0, stream>>>(psi_w1, psi_w2, phi_w1, phi_w2, ws);
    k_triplet<<<(T_TRIP + 63) / 64, 256, 0, stream>>>(
        h_pair, ivu, iuw, ivw, geom,
        ws + PSI_W1T_OFF, ws + PSI_W2T_OFF, psi_b1, psi_b2, out);
    k_pair<<<(NP + 63) / 64, 256, 0, stream>>>(
        h_pair, ws + PHI_W1T_OFF, ws + PHI_W2T_OFF, phi_b1, phi_b2, out);
  }
}

// Round 6
// 286.604 us; speedup vs baseline: 1.4261x; 1.3131x over previous
//
#include <hip/hip_runtime.h>
#include <hip/hip_bf16.h>

#define T_TRIP 500000
#define NP     100000
#define NTILES 7813    // ceil(T_TRIP/64)
#define NPAD   500032  // NTILES*64

typedef float f32x4 __attribute__((ext_vector_type(4)));
typedef __bf16 bf16x8 __attribute__((ext_vector_type(8)));
typedef unsigned short u16;
typedef unsigned short u16x8 __attribute__((ext_vector_type(8)));
typedef unsigned int u32;

__device__ __forceinline__ u16 f2bf(float f) {
  union { float f; unsigned u; } v; v.f = f;
  unsigned r = v.u + 0x7fffu + ((v.u >> 16) & 1u);
  return (u16)(r >> 16);
}

__device__ __forceinline__ ushort4 cvt4(float4 v) {
  ushort4 o; o.x = f2bf(v.x); o.y = f2bf(v.y); o.z = f2bf(v.z); o.w = f2bf(v.w);
  return o;
}

__device__ __forceinline__ u16 cvt1_pk(float v) {
  unsigned r;
  asm("v_cvt_pk_bf16_f32 %0, %1, %1" : "=v"(r) : "v"(v));
  return (u16)r;
}

__device__ __forceinline__ float bflo(u32 d) {
  union { u32 u; float f; } v; v.u = d << 16; return v.f;
}
__device__ __forceinline__ float bfhi(u32 d) {
  union { u32 u; float f; } v; v.u = d & 0xffff0000u; return v.f;
}

#define MFMA16(a, b, c) __builtin_amdgcn_mfma_f32_16x16x32_bf16((a), (b), (c), 0, 0, 0)

#define WAITVM(N) asm volatile("s_waitcnt vmcnt(" #N ")" ::: "memory")
#define LGKM0()   asm volatile("s_waitcnt lgkmcnt(0)" ::: "memory")

__device__ __forceinline__ void barrier_raw() {
  asm volatile("" ::: "memory");
  __builtin_amdgcn_s_barrier();
  asm volatile("" ::: "memory");
  __builtin_amdgcn_sched_barrier(0);
}

__device__ __forceinline__ void gload_lds16(const u16* g, u16* l) {
  __builtin_amdgcn_global_load_lds((const __attribute__((address_space(1))) void*)g,
                                   (__attribute__((address_space(3))) void*)l, 16, 0, 0);
}
__device__ __forceinline__ void gload_lds4(const int* g, int* l) {
  __builtin_amdgcn_global_load_lds((const __attribute__((address_space(1))) void*)g,
                                   (__attribute__((address_space(3))) void*)l, 4, 0, 0);
}

// =================== ws layout ===================
#define FP_W1A   0u
#define FP_W1B   16384u
#define FP_W1C   32768u
#define FP_W2    49152u
#define FP_PW1   65536u
#define FP_PW2   98304u
#define FP_W1D   114688u    // f32 [4][128]
#define FP_H     131072u    // h_pair bf16 [NP][128]
#define FP_AGG   12931072u  // agg bf16 [NP][128]
// sorted-path byte offsets:
#define SB_CNT2    51462144ull
#define SB_CURSOR2 51862144ull
#define SB_BSUM2   52262144ull
#define SB_TRIP    52262656ull          // 16B packed AoS per triplet, NPAD entries
#define WS_S2      60263168ull

#define HSTR   136   // pair-kernel hidden stride (u16)
#define HSTR2  132   // triplet hidden/m stride (u16); 66 dw
#define GSTR   520   // XB group stride (u16)
#define X2STR  264   // pair-input tile stride (u16)

// ---------------- fused pre: weights + hconv/aggzero + hist ----------------
__global__ void k_pre(const float* __restrict__ psi_w1, const float* __restrict__ psi_w2,
                      const float* __restrict__ phi_w1, const float* __restrict__ phi_w2,
                      const float* __restrict__ h, const int* __restrict__ ivw,
                      u16* __restrict__ ws, int* __restrict__ cnt) {
  const int b = blockIdx.x;
  if (b < 450) {                       // ---- weight prep ----
    int i = b * 256 + threadIdx.x;
    if (i < 49152) {
      int s = i / 16384, r = i % 16384;
      int n = r / 128, k = r % 128;
      ws[FP_W1A + i] = f2bf(psi_w1[(s * 128 + k) * 128 + n]);
      return;
    }
    i -= 49152;
    if (i < 16384) {
      int n = i / 128, k = i % 128;
      ws[FP_W2 + i] = f2bf(psi_w2[k * 128 + n]);
      return;
    }
    i -= 16384;
    if (i < 32768) {
      int n = i / 256, k = i % 256;
      ws[FP_PW1 + i] = f2bf(phi_w1[k * 128 + n]);
      return;
    }
    i -= 32768;
    if (i < 16384) {
      int n = i / 128, k = i % 128;
      ws[FP_PW2 + i] = f2bf(phi_w2[k * 128 + n]);
      return;
    }
    i -= 16384;
    if (i < 512) {
      int k = i / 128, n = i % 128;
      reinterpret_cast<float*>(ws + FP_W1D)[i] = psi_w1[(384 + k) * 128 + n];
    }
  } else if (b < 6700) {               // ---- h->bf16 + zero AGG ----
    const size_t i = (size_t)((b - 450) * 256 + threadIdx.x) * 8;
    float4 v0 = *reinterpret_cast<const float4*>(h + i);
    float4 v1 = *reinterpret_cast<const float4*>(h + i + 4);
    *reinterpret_cast<ushort4*>(ws + FP_H + i)     = cvt4(v0);
    *reinterpret_cast<ushort4*>(ws + FP_H + i + 4) = cvt4(v1);
    ushort4 z = {0, 0, 0, 0};
    *reinterpret_cast<ushort4*>(ws + FP_AGG + i)     = z;
    *reinterpret_cast<ushort4*>(ws + FP_AGG + i + 4) = z;
  } else {                             // ---- histogram ----
    int i = (b - 6700) * 256 + threadIdx.x;
    if (i < T_TRIP) atomicAdd(&cnt[ivw[i]], 1);
  }
}

// ================= scan =================
__global__ __launch_bounds__(1024) void k_scan1(const int* __restrict__ cnt,
                                                int* __restrict__ cursor, int* __restrict__ bsum) {
  __shared__ int wsum[16];
  const int idx = blockIdx.x * 1024 + threadIdx.x;
  const int lane = threadIdx.x & 63, wid = threadIdx.x >> 6;
  int v = (idx < NP) ? cnt[idx] : 0;
  int x = v;
#pragma unroll
  for (int off = 1; off < 64; off <<= 1) {
    int n = __shfl_up(x, off);
    if (lane >= off) x += n;
  }
  if (lane == 63) wsum[wid] = x;
  __syncthreads();
  if (threadIdx.x < 16) {
    int s = wsum[threadIdx.x];
#pragma unroll
    for (int off = 1; off < 16; off <<= 1) {
      int n = __shfl_up(s, off);
      if (threadIdx.x >= off) s += n;
    }
    wsum[threadIdx.x] = s;
  }
  __syncthreads();
  const int base = wid ? wsum[wid - 1] : 0;
  if (idx < NP) cursor[idx] = base + x - v;
  if (threadIdx.x == 1023) bsum[blockIdx.x] = base + x;
}

__global__ void k_scan2(int* __restrict__ bsum) {
  __shared__ int s[128];
  const int t = threadIdx.x;
  int v = (t < 98) ? bsum[t] : 0;
  s[t] = v; __syncthreads();
#pragma unroll
  for (int off = 1; off < 128; off <<= 1) {
    int a = (t >= off) ? s[t - off] : 0;
    __syncthreads();
    s[t] += a;
    __syncthreads();
  }
  if (t < 98) bsum[t] = s[t] - v;
}

__global__ void k_scan3(const int* __restrict__ bsum, int* __restrict__ cursor) {
  int idx = blockIdx.x * 256 + threadIdx.x;
  if (idx < NP) cursor[idx] += bsum[idx >> 10];
}

// ================= permute -> 16B packed AoS =================
// d0 = ivu | (ivw&0x7fff)<<17 ; d1 = iuw | (ivw>>15)<<17 ; d2,d3 = geom bf16x4
__global__ void k_perm_pack(const int* __restrict__ ivu, const int* __restrict__ iuw,
                            const int* __restrict__ ivw, const float* __restrict__ geom,
                            int* __restrict__ cursor, int4* __restrict__ trip) {
  int i = blockIdx.x * 256 + threadIdx.x;
  if (i < T_TRIP) {
    int v = ivw[i];
    int pos = atomicAdd(&cursor[v], 1);
    float4 g = reinterpret_cast<const float4*>(geom)[i];
    u32 pk0, pk1;
    asm("v_cvt_pk_bf16_f32 %0, %1, %2" : "=v"(pk0) : "v"(g.x), "v"(g.y));
    asm("v_cvt_pk_bf16_f32 %0, %1, %2" : "=v"(pk1) : "v"(g.z), "v"(g.w));
    int4 rec;
    rec.x = ivu[i] | ((v & 0x7fff) << 17);
    rec.y = iuw[i] | ((v >> 15) << 17);
    rec.z = (int)pk0;
    rec.w = (int)pk1;
    trip[pos] = rec;
  } else if (i < NPAD) {
    int4 z = {0, 0, 0, 0};
    trip[i] = z;
  }
}

// ================= sorted triplet kernel with in-tile segmented aggregation =================
__global__ __launch_bounds__(256, 3) void k_triplet_sortagg(
    const u16* __restrict__ H, const int* __restrict__ trip,
    const u16* __restrict__ W1A, const u16* __restrict__ W1B, const u16* __restrict__ W1C,
    const float* __restrict__ w1dF, const u16* __restrict__ W2T,
    const float* __restrict__ b1, const float* __restrict__ b2,
    u16* __restrict__ AGG) {
  __shared__ __align__(16) u16 XB[2][16 * GSTR];   // 33280 B
  __shared__ __align__(16) u16 hl[64 * HSTR2];     // 16896 B (also m-tile)
  __shared__ __align__(16) int aosT[2][256];       //  2048 B   total 52224 B

  u32* mlu = reinterpret_cast<u32*>(hl);

  const int tid = threadIdx.x;
  const int w = tid >> 6, l = tid & 63;
  const int lr = l & 15;
  const int lk = (l >> 4) << 3;
  const int n0 = w * 32 + lr;
  const int rowh = (l >> 4) << 2;
  const int srow = l >> 4;
  const int schunk = (l & 15) ^ ((l >> 4) << 1);

  // hoisted constants (W2 frags in regs -> GEMM2 has no vmem)
  bf16x8 w2f[4][2];
#pragma unroll
  for (int ks = 0; ks < 4; ++ks)
#pragma unroll
    for (int ct = 0; ct < 2; ++ct)
      w2f[ks][ct] = *reinterpret_cast<const bf16x8*>(&W2T[(size_t)(n0 + ct * 16) * 128 + ks * 32 + lk]);
  const float b1v[2] = {b1[n0], b1[n0 + 16]};
  const float b2v[2] = {b2[n0], b2[n0 + 16]};
  float w1dv[4][2];
#pragma unroll
  for (int k = 0; k < 4; ++k) {
    w1dv[k][0] = w1dF[k * 128 + n0];
    w1dv[k][1] = w1dF[k * 128 + n0 + 16];
  }

  auto get_idx = [&](int cb, int r, int sel) -> int {
    if (sel == 0) return aosT[cb][r * 4] & 0x1FFFF;
    if (sel == 1) return aosT[cb][r * 4 + 1] & 0x1FFFF;
    u32 d0 = (u32)aosT[cb][r * 4], d1 = (u32)aosT[cb][r * 4 + 1];
    return (int)((d0 >> 17) | ((d1 >> 17) << 15));
  };

  auto stage_src = [&](int cb, int sel, int buf) {
#pragma unroll
    for (int q = 0; q < 4; ++q) {
      const int g = w * 4 + q;
      const int idx = get_idx(cb, g * 4 + srow, sel);      // LDS broadcast
      gload_lds16(H + (size_t)idx * 128 + schunk * 8, &XB[buf][g * GSTR]);
    }
  };

  auto stage_aos = [&](int tile, int cb) {                  // exactly 1 vm-op per wave
    const int* src = trip + (size_t)tile * 256;
    gload_lds4(src + w * 64 + l, &aosT[cb][w * 64]);
  };

  auto gemm_src = [&](const u16* WT, int buf, f32x4 (&acc)[4][2]) {
#pragma unroll
    for (int ks = 0; ks < 4; ++ks) {
      bf16x8 a[4], b[2];
#pragma unroll
      for (int rt = 0; rt < 4; ++rt) {
        const int r = rt * 16 + lr;
        const int g = r >> 2, s = r & 3;
        const int j = ks * 4 + (l >> 4);
        a[rt] = *reinterpret_cast<const bf16x8*>(&XB[buf][g * GSTR + s * 128 + ((j ^ (s << 1)) << 3)]);
      }
#pragma unroll
      for (int ct = 0; ct < 2; ++ct)
        b[ct] = *reinterpret_cast<const bf16x8*>(&WT[(size_t)(n0 + ct * 16) * 128 + ks * 32 + lk]);
#pragma unroll
      for (int rt = 0; rt < 4; ++rt)
#pragma unroll
        for (int ct = 0; ct < 2; ++ct)
          acc[rt][ct] = MFMA16(a[rt], b[ct], acc[rt][ct]);
    }
  };

  int cur = 0, pb = 0;
  int tt = blockIdx.x;
  const int G = gridDim.x;

  // ---- prologue: AoS tiles t and t+G, then s0(t) ----
  {
    int t1 = tt + G; if (t1 >= NTILES) t1 = NTILES - 1;
    stage_aos(tt, 0);
    stage_aos(t1, 1);
    WAITVM(0);
    barrier_raw();
    stage_src(0, 0 /*ivu*/, 0);
  }

  for (; tt < NTILES; tt += G) {
    const int t0 = tt * 64;

    stage_src(cur, 1 /*iuw*/, pb ^ 1);       // A: s1(t)
    WAITVM(4);                               // s0 resident
    barrier_raw();

    f32x4 acc[4][2] = {};
    gemm_src(W1A, pb, acc);                  // D
    barrier_raw();                           // XB[pb] free

    stage_src(cur, 2 /*ivw*/, pb);           // F: s2(t)
    WAITVM(4);                               // s1 resident
    barrier_raw();

    gemm_src(W1B, pb ^ 1, acc);              // I
    WAITVM(0);                               // s2 resident
    barrier_raw();                           // XB[pb^1] free

    stage_src(cur ^ 1, 0 /*ivu*/, pb ^ 1);   // L: s0(t+1)
    gemm_src(W1C, pb, acc);                  // M

    // N: geom (bf16 from AoS) + bias + silu -> hl
#pragma unroll
    for (int rt = 0; rt < 4; ++rt)
#pragma unroll
      for (int j = 0; j < 4; ++j) {
        const int row = rt * 16 + rowh + j;
        const u32 d2 = (u32)aosT[cur][row * 4 + 2];
        const u32 d3 = (u32)aosT[cur][row * 4 + 3];
        const float gx = bflo(d2), gy = bfhi(d2), gz = bflo(d3), gw = bfhi(d3);
#pragma unroll
        for (int ct = 0; ct < 2; ++ct)
          acc[rt][ct][j] += gx * w1dv[0][ct] + gy * w1dv[1][ct] +
                            gz * w1dv[2][ct] + gw * w1dv[3][ct];
      }
#pragma unroll
    for (int rt = 0; rt < 4; ++rt)
#pragma unroll
      for (int ct = 0; ct < 2; ++ct) {
        const float bb = b1v[ct];
#pragma unroll
        for (int j = 0; j < 4; ++j) {
          float v = acc[rt][ct][j] + bb;
          v = v * __builtin_amdgcn_rcpf(1.f + __expf(-v));
          hl[(rt * 16 + rowh + j) * HSTR2 + n0 + ct * 16] = cvt1_pk(v);
        }
      }
    LGKM0();
    barrier_raw();

    // P: GEMM2 (hl + reg W2)
    f32x4 acc2[4][2] = {};
#pragma unroll
    for (int ks = 0; ks < 4; ++ks) {
      bf16x8 a[4];
#pragma unroll
      for (int rt = 0; rt < 4; ++rt)
        a[rt] = *reinterpret_cast<const bf16x8*>(&hl[(rt * 16 + lr) * HSTR2 + ks * 32 + lk]);
#pragma unroll
      for (int rt = 0; rt < 4; ++rt)
#pragma unroll
        for (int ct = 0; ct < 2; ++ct)
          acc2[rt][ct] = MFMA16(a[rt], w2f[ks][ct], acc2[rt][ct]);
    }
    barrier_raw();                           // hl readers done -> reuse as m-tile

    // Q: pack bf16 pairs -> m-tile in LDS (stride 66 dwords)
#pragma unroll
    for (int rt = 0; rt < 4; ++rt)
#pragma unroll
      for (int j = 0; j < 4; ++j) {
        const int row = rt * 16 + rowh + j;
        float v0 = acc2[rt][0][j] + b2v[0];
        float v1 = acc2[rt][1][j] + b2v[1];
        float x0 = __shfl_xor(v0, 1);
        float x1 = __shfl_xor(v1, 1);
        const bool even = (l & 1) == 0;
        float lo = even ? v0 : x1;
        float hi = even ? x0 : v1;
        const int dcol = even ? (n0 >> 1) : ((n0 + 15) >> 1);
        u32 pk;
        asm("v_cvt_pk_bf16_f32 %0, %1, %2" : "=v"(pk) : "v"(lo), "v"(hi));
        mlu[row * 66 + dcol] = pk;
      }
    LGKM0();
    barrier_raw();

    // R: segmented reduce over sorted vw; one pk-atomic per run per packed col
    {
      auto get_vw = [&](int r) -> int {
        u32 d0 = (u32)aosT[cur][r * 4], d1 = (u32)aosT[cur][r * 4 + 1];
        return (int)((d0 >> 17) | ((d1 >> 17) << 15));
      };
      float lo = 0.f, hi = 0.f;
      int vwc = get_vw(w * 16);
#pragma unroll 1
      for (int r8 = 0; r8 < 16; ++r8) {
        const int row = w * 16 + r8;
        const u32 d = mlu[row * 66 + l];
        if (t0 + row < T_TRIP) { lo += bflo(d); hi += bfhi(d); }
        const int vwn = (row < 63) ? get_vw(row + 1) : -1;
        if ((r8 == 15) || (vwn != vwc)) {
          u16* p = AGG + (size_t)vwc * 128 + l * 2;
          u32 pk;
          asm("v_cvt_pk_bf16_f32 %0, %1, %2" : "=v"(pk) : "v"(lo), "v"(hi));
          asm volatile("global_atomic_pk_add_bf16 %0, %1, off" :: "v"(p), "v"(pk) : "memory");
          lo = 0.f; hi = 0.f; vwc = vwn;
        }
      }
    }
    barrier_raw();                           // aosT[cur] free

    // O: AoS prefetch tile t+2G into aosT[cur]
    {
      int t2 = tt + 2 * G; if (t2 >= NTILES) t2 = NTILES - 1;
      stage_aos(t2, cur);
    }

    WAITVM(0);                               // Z: drain L + atomics + O
    barrier_raw();
    pb ^= 1; cur ^= 1;
  }
  WAITVM(0);
}

// ================= pair kernel (R2-proven) =================
__global__ __launch_bounds__(256, 3) void k_pair_fast(
    const float* __restrict__ h_pair, const u16* __restrict__ H, const u16* __restrict__ AGG,
    const u16* __restrict__ PW1T, const u16* __restrict__ PW2T,
    const float* __restrict__ b1, const float* __restrict__ b2,
    float* __restrict__ out) {
  __shared__ __align__(16) u16 xl[64 * X2STR];
  __shared__ __align__(16) u16 hl[64 * HSTR];

  const int tid = threadIdx.x;
  const int r0 = blockIdx.x * 64;

  {
    const int row = tid >> 2, q = tid & 3;
    int rc = r0 + row; rc = (rc < NP) ? rc : (NP - 1);
    const u16x8* sh = reinterpret_cast<const u16x8*>(H + (size_t)rc * 128 + q * 32);
    const u16x8* sa = reinterpret_cast<const u16x8*>(AGG + (size_t)rc * 128 + q * 32);
    u16x8* d1 = reinterpret_cast<u16x8*>(&xl[row * X2STR + q * 32]);
    u16x8* d2 = reinterpret_cast<u16x8*>(&xl[row * X2STR + 128 + q * 32]);
#pragma unroll
    for (int i = 0; i < 4; ++i) { d1[i] = sh[i]; d2[i] = sa[i]; }
  }
  __syncthreads();

  const int w = tid >> 6, l = tid & 63;
  const int lr = l & 15;
  const int lk = (l >> 4) << 3;
  const int n0 = w * 32 + lr;
  const int rowh = (l >> 4) << 2;

  f32x4 acc[4][2] = {};
#pragma unroll 1
  for (int ks = 0; ks < 8; ++ks) {
    const int k0 = ks * 32;
    bf16x8 a[4], b[2];
#pragma unroll
    for (int rt = 0; rt < 4; ++rt)
      a[rt] = *reinterpret_cast<const bf16x8*>(&xl[(rt * 16 + lr) * X2STR + k0 + lk]);
#pragma unroll
    for (int ct = 0; ct < 2; ++ct)
      b[ct] = *reinterpret_cast<const bf16x8*>(&PW1T[(size_t)(n0 + ct * 16) * 256 + k0 + lk]);
#pragma unroll
    for (int rt = 0; rt < 4; ++rt)
#pragma unroll
      for (int ct = 0; ct < 2; ++ct)
        acc[rt][ct] = MFMA16(a[rt], b[ct], acc[rt][ct]);
  }

  {
    const float b1v0 = b1[n0], b1v1 = b1[n0 + 16];
#pragma unroll
    for (int rt = 0; rt < 4; ++rt)
#pragma unroll
      for (int ct = 0; ct < 2; ++ct) {
        const float bb = ct ? b1v1 : b1v0;
#pragma unroll
        for (int j = 0; j < 4; ++j) {
          float v = acc[rt][ct][j] + bb;
          v = v * __builtin_amdgcn_rcpf(1.f + __expf(-v));
          hl[(rt * 16 + rowh + j) * HSTR + n0 + ct * 16] = cvt1_pk(v);
        }
      }
  }
  __syncthreads();

  f32x4 acc2[4][2] = {};
#pragma unroll
  for (int ks = 0; ks < 4; ++ks) {
    const int k0 = ks * 32;
    bf16x8 a[4], b[2];
#pragma unroll
    for (int rt = 0; rt < 4; ++rt)
      a[rt] = *reinterpret_cast<const bf16x8*>(&hl[(rt * 16 + lr) * HSTR + k0 + lk]);
#pragma unroll
    for (int ct = 0; ct < 2; ++ct)
      b[ct] = *reinterpret_cast<const bf16x8*>(&PW2T[(size_t)(n0 + ct * 16) * 128 + k0 + lk]);
#pragma unroll
    for (int rt = 0; rt < 4; ++rt)
#pragma unroll
      for (int ct = 0; ct < 2; ++ct)
        acc2[rt][ct] = MFMA16(a[rt], b[ct], acc2[rt][ct]);
  }

  {
    const float b2v0 = b2[n0], b2v1 = b2[n0 + 16];
#pragma unroll
    for (int rt = 0; rt < 4; ++rt)
#pragma unroll
      for (int j = 0; j < 4; ++j) {
        const int row = rt * 16 + rowh + j;
        const int r = r0 + row;
        if (r < NP) {
          out[(size_t)r * 128 + n0]      = h_pair[(size_t)r * 128 + n0]      + acc2[rt][0][j] + b2v0;
          out[(size_t)r * 128 + n0 + 16] = h_pair[(size_t)r * 128 + n0 + 16] + acc2[rt][1][j] + b2v1;
        }
      }
  }
}

// ===================== R0 fallback (tiny ws) =====================
#define PSI_W1T_OFF 0
#define PSI_W2T_OFF 53248
#define PHI_W1T_OFF 69632
#define PHI_W2T_OFF 102400
#define WS_U16_TOTAL 118784
#define XSTR 424

__global__ void k_prep(const float* __restrict__ psi_w1, const float* __restrict__ psi_w2,
                       const float* __restrict__ phi_w1, const float* __restrict__ phi_w2,
                       u16* __restrict__ ws) {
  int i = blockIdx.x * 256 + threadIdx.x;
  if (i < 128 * 416) {
    int n = i / 416, k = i % 416;
    ws[PSI_W1T_OFF + i] = f2bf(k < 388 ? psi_w1[k * 128 + n] : 0.f);
    return;
  }
  i -= 128 * 416;
  if (i < 128 * 128) {
    int n = i / 128, k = i % 128;
    ws[PSI_W2T_OFF + i] = f2bf(psi_w2[k * 128 + n]);
    return;
  }
  i -= 128 * 128;
  if (i < 128 * 256) {
    int n = i / 256, k = i % 256;
    ws[PHI_W1T_OFF + i] = f2bf(phi_w1[k * 128 + n]);
    return;
  }
  i -= 128 * 256;
  if (i < 128 * 128) {
    int n = i / 128, k = i % 128;
    ws[PHI_W2T_OFF + i] = f2bf(phi_w2[k * 128 + n]);
  }
}

__global__ __launch_bounds__(256, 2) void k_triplet(
    const float* __restrict__ h_pair,
    const int* __restrict__ ivu, const int* __restrict__ iuw, const int* __restrict__ ivw,
    const float* __restrict__ geom,
    const u16* __restrict__ W1T, const u16* __restrict__ W2T,
    const float* __restrict__ b1, const float* __restrict__ b2,
    float* __restrict__ agg) {
  __shared__ __align__(16) u16 xl[64 * XSTR];
  __shared__ __align__(16) u16 hl[64 * HSTR];
  __shared__ int svw[64];

  const int tid = threadIdx.x;
  const int t0 = blockIdx.x * 64;

  {
    const int row = tid >> 2, q = tid & 3;
    const int t = t0 + row;
    const int tc = (t < T_TRIP) ? t : (T_TRIP - 1);
    if (q == 0) svw[row] = (t < T_TRIP) ? ivw[tc] : -1;
    int idx[3];
    idx[0] = ivu[tc]; idx[1] = iuw[tc]; idx[2] = ivw[tc];
#pragma unroll
    for (int s = 0; s < 3; ++s) {
      const float4* src = reinterpret_cast<const float4*>(h_pair + (size_t)idx[s] * 128 + q * 32);
      u16* dst = &xl[row * XSTR + s * 128 + q * 32];
#pragma unroll
      for (int i = 0; i < 8; ++i)
        *reinterpret_cast<ushort4*>(dst + i * 4) = cvt4(src[i]);
    }
  }
  if (tid < 64) {
    const int t = t0 + tid;
    const int tc = (t < T_TRIP) ? t : (T_TRIP - 1);
    const float4 g = reinterpret_cast<const float4*>(geom)[tc];
    u16* dst = &xl[tid * XSTR + 384];
    *reinterpret_cast<ushort4*>(dst) = cvt4(g);
    ushort4 z = {0, 0, 0, 0};
#pragma unroll
    for (int i = 1; i < 8; ++i) *reinterpret_cast<ushort4*>(dst + i * 4) = z;
  }
  __syncthreads();

  const int w = tid >> 6;
  const int l = tid & 63;
  const int lr = l & 15;
  const int lk = (l >> 4) << 3;
  const int n0 = w * 32 + lr;
  const int rowh = (l >> 4) << 2;

  f32x4 acc[4][2] = {};
#pragma unroll 1
  for (int ks = 0; ks < 13; ++ks) {
    const int k0 = ks * 32;
    bf16x8 a[4], b[2];
#pragma unroll
    for (int rt = 0; rt < 4; ++rt)
      a[rt] = *reinterpret_cast<const bf16x8*>(&xl[(rt * 16 + lr) * XSTR + k0 + lk]);
#pragma unroll
    for (int ct = 0; ct < 2; ++ct)
      b[ct] = *reinterpret_cast<const bf16x8*>(&W1T[(size_t)(n0 + ct * 16) * 416 + k0 + lk]);
#pragma unroll
    for (int rt = 0; rt < 4; ++rt)
#pragma unroll
      for (int ct = 0; ct < 2; ++ct)
        acc[rt][ct] = MFMA16(a[rt], b[ct], acc[rt][ct]);
  }

  {
    const float b1v0 = b1[n0], b1v1 = b1[n0 + 16];
#pragma unroll
    for (int rt = 0; rt < 4; ++rt)
#pragma unroll
      for (int ct = 0; ct < 2; ++ct) {
        const float bb = ct ? b1v1 : b1v0;
#pragma unroll
        for (int j = 0; j < 4; ++j) {
          float v = acc[rt][ct][j] + bb;
          v = v / (1.f + __expf(-v));
          hl[(rt * 16 + rowh + j) * HSTR + n0 + ct * 16] = f2bf(v);
        }
      }
  }
  __syncthreads();

  f32x4 acc2[4][2] = {};
#pragma unroll
  for (int ks = 0; ks < 4; ++ks) {
    const int k0 = ks * 32;
    bf16x8 a[4], b[2];
#pragma unroll
    for (int rt = 0; rt < 4; ++rt)
      a[rt] = *reinterpret_cast<const bf16x8*>(&hl[(rt * 16 + lr) * HSTR + k0 + lk]);
#pragma unroll
    for (int ct = 0; ct < 2; ++ct)
      b[ct] = *reinterpret_cast<const bf16x8*>(&W2T[(size_t)(n0 + ct * 16) * 128 + k0 + lk]);
#pragma unroll
    for (int rt = 0; rt < 4; ++rt)
#pragma unroll
      for (int ct = 0; ct < 2; ++ct)
        acc2[rt][ct] = MFMA16(a[rt], b[ct], acc2[rt][ct]);
  }

  {
    const float b2v0 = b2[n0], b2v1 = b2[n0 + 16];
#pragma unroll
    for (int rt = 0; rt < 4; ++rt)
#pragma unroll
      for (int j = 0; j < 4; ++j) {
        const int row = rt * 16 + rowh + j;
        const int dst = svw[row];
        if (dst >= 0) {
          unsafeAtomicAdd(&agg[(size_t)dst * 128 + n0], acc2[rt][0][j] + b2v0);
          unsafeAtomicAdd(&agg[(size_t)dst * 128 + n0 + 16], acc2[rt][1][j] + b2v1);
        }
      }
  }
}

__global__ __launch_bounds__(256, 2) void k_pair(
    const float* __restrict__ h_pair,
    const u16* __restrict__ W1T, const u16* __restrict__ W2T,
    const float* __restrict__ b1, const float* __restrict__ b2,
    float* __restrict__ out) {
  __shared__ __align__(16) u16 xl[64 * X2STR];
  __shared__ __align__(16) u16 hl[64 * HSTR];

  const int tid = threadIdx.x;
  const int r0 = blockIdx.x * 64;

  {
    const int row = tid >> 2, q = tid & 3;
    const int r = r0 + row;
    const int rc = (r < NP) ? r : (NP - 1);
    const float4* s1 = reinterpret_cast<const float4*>(h_pair + (size_t)rc * 128 + q * 32);
    const float4* s2 = reinterpret_cast<const float4*>(out + (size_t)rc * 128 + q * 32);
    u16* d1 = &xl[row * X2STR + q * 32];
    u16* d2 = &xl[row * X2STR + 128 + q * 32];
#pragma unroll
    for (int i = 0; i < 8; ++i) {
      *reinterpret_cast<ushort4*>(d1 + i * 4) = cvt4(s1[i]);
      *reinterpret_cast<ushort4*>(d2 + i * 4) = cvt4(s2[i]);
    }
  }
  __syncthreads();

  const int w = tid >> 6;
  const int l = tid & 63;
  const int lr = l & 15;
  const int lk = (l >> 4) << 3;
  const int n0 = w * 32 + lr;
  const int rowh = (l >> 4) << 2;

  f32x4 acc[4][2] = {};
#pragma unroll 1
  for (int ks = 0; ks < 8; ++ks) {
    const int k0 = ks * 32;
    bf16x8 a[4], b[2];
#pragma unroll
    for (int rt = 0; rt < 4; ++rt)
      a[rt] = *reinterpret_cast<const bf16x8*>(&xl[(rt * 16 + lr) * X2STR + k0 + lk]);
#pragma unroll
    for (int ct = 0; ct < 2; ++ct)
      b[ct] = *reinterpret_cast<const bf16x8*>(&W1T[(size_t)(n0 + ct * 16) * 256 + k0 + lk]);
#pragma unroll
    for (int rt = 0; rt < 4; ++rt)
#pragma unroll
      for (int ct = 0; ct < 2; ++ct)
        acc[rt][ct] = MFMA16(a[rt], b[ct], acc[rt][ct]);
  }

  {
    const float b1v0 = b1[n0], b1v1 = b1[n0 + 16];
#pragma unroll
    for (int rt = 0; rt < 4; ++rt)
#pragma unroll
      for (int ct = 0; ct < 2; ++ct) {
        const float bb = ct ? b1v1 : b1v0;
#pragma unroll
        for (int j = 0; j < 4; ++j) {
          float v = acc[rt][ct][j] + bb;
          v = v / (1.f + __expf(-v));
          hl[(rt * 16 + rowh + j) * HSTR + n0 + ct * 16] = f2bf(v);
        }
      }
  }
  __syncthreads();

  f32x4 acc2[4][2] = {};
#pragma unroll
  for (int ks = 0; ks < 4; ++ks) {
    const int k0 = ks * 32;
    bf16x8 a[4], b[2];
#pragma unroll
    for (int rt = 0; rt < 4; ++rt)
      a[rt] = *reinterpret_cast<const bf16x8*>(&hl[(rt * 16 + lr) * HSTR + k0 + lk]);
#pragma unroll
    for (int ct = 0; ct < 2; ++ct)
      b[ct] = *reinterpret_cast<const bf16x8*>(&W2T[(size_t)(n0 + ct * 16) * 128 + k0 + lk]);
#pragma unroll
    for (int rt = 0; rt < 4; ++rt)
#pragma unroll
      for (int ct = 0; ct < 2; ++ct)
        acc2[rt][ct] = MFMA16(a[rt], b[ct], acc2[rt][ct]);
  }

  {
    const float b2v0 = b2[n0], b2v1 = b2[n0 + 16];
#pragma unroll
    for (int rt = 0; rt < 4; ++rt)
#pragma unroll
      for (int j = 0; j < 4; ++j) {
        const int row = rt * 16 + rowh + j;
        const int r = r0 + row;
        if (r < NP) {
          out[(size_t)r * 128 + n0]      = h_pair[(size_t)r * 128 + n0]      + acc2[rt][0][j] + b2v0;
          out[(size_t)r * 128 + n0 + 16] = h_pair[(size_t)r * 128 + n0 + 16] + acc2[rt][1][j] + b2v1;
        }
      }
  }
}

extern "C" void kernel_launch(void* const* d_in, const int* in_sizes, int n_in,
                              void* d_out, int out_size, void* d_ws, size_t ws_size,
                              hipStream_t stream) {
  const float* h_pair = (const float*)d_in[0];
  const int* ivu = (const int*)d_in[1];
  const int* iuw = (const int*)d_in[2];
  const int* ivw = (const int*)d_in[3];
  const float* geom = (const float*)d_in[4];
  const float* psi_w1 = (const float*)d_in[5];
  const float* psi_b1 = (const float*)d_in[6];
  const float* psi_w2 = (const float*)d_in[7];
  const float* psi_b2 = (const float*)d_in[8];
  const float* phi_w1 = (const float*)d_in[9];
  const float* phi_b1 = (const float*)d_in[10];
  const float* phi_w2 = (const float*)d_in[11];
  const float* phi_b2 = (const float*)d_in[12];

  float* out = (float*)d_out;
  u16* ws = (u16*)d_ws;
  char* wsb = (char*)d_ws;

  if (ws_size >= WS_S2) {
    int*  cnt    = (int*)(wsb + SB_CNT2);
    int*  cursor = (int*)(wsb + SB_CURSOR2);
    int*  bsum   = (int*)(wsb + SB_BSUM2);
    int4* trip   = (int4*)(wsb + SB_TRIP);

    hipMemsetAsync(cnt, 0, NP * sizeof(int), stream);
    k_pre<<<8654, 256, 0, stream>>>(psi_w1, psi_w2, phi_w1, phi_w2, h_pair, ivw, ws, cnt);
    k_scan1<<<98, 1024, 0, stream>>>(cnt, cursor, bsum);
    k_scan2<<<1, 128, 0, stream>>>(bsum);
    k_scan3<<<391, 256, 0, stream>>>(bsum, cursor);
    k_perm_pack<<<(NPAD + 255) / 256, 256, 0, stream>>>(ivu, iuw, ivw, geom, cursor, trip);
    k_triplet_sortagg<<<768, 256, 0, stream>>>(
        ws + FP_H, (const int*)trip,
        ws + FP_W1A, ws + FP_W1B, ws + FP_W1C,
        reinterpret_cast<const float*>(ws + FP_W1D), ws + FP_W2,
        psi_b1, psi_b2, ws + FP_AGG);
    k_pair_fast<<<(NP + 63) / 64, 256, 0, stream>>>(
        h_pair, ws + FP_H, ws + FP_AGG,
        ws + FP_PW1, ws + FP_PW2, phi_b1, phi_b2, out);
  } else {
    // ---------- R0 fallback ----------
    hipMemsetAsync(d_out, 0, (size_t)out_size * sizeof(float), stream);
    k_prep<<<(WS_U16_TOTAL + 255) / 256, 256, 0, stream>>>(psi_w1, psi_w2, phi_w1, phi_w2, ws);
    k_triplet<<<(T_TRIP + 63) / 64, 256, 0, stream>>>(
        h_pair, ivu, iuw, ivw, geom,
        ws + PSI_W1T_OFF, ws + PSI_W2T_OFF, psi_b1, psi_b2, out);
    k_pair<<<(NP + 63) / 64, 256, 0, stream>>>(
        h_pair, ws + PHI_W1T_OFF, ws + PHI_W2T_OFF, phi_b1, phi_b2, out);
  }
}